// Round 8
// baseline (77.123 us; speedup 1.0000x reference)
//
#include <hip/hip_runtime.h>
#include <math.h>

// CausalAttention: q/k/v = X @ W^T, RoPE(q,k), flash causal attention.
// B=4 T=2048 E=1024 D=128, f32 in/out, bf16 MFMA internally.
// Round 8: LDS-FREE proj — W (0.75MB) + per-XCD X slice (2MB) are L2-resident,
// so each wave streams A/B frags directly from L2 (b128 loads), no barriers,
// 2-deep named-reg pipeline. 1024 waves (64x48 tiles), XCD-chunked.
// Precast XCD-aligned so Xb is written by the same XCD that reads it.

#define B_ 4
#define T_ 2048
#define E_ 1024
#define D_ 128
#define BT_ (B_ * T_)

#define UNITS_PER_B 160   // sum over qi of ceil(tiles(qi)/8), tiles(qi)=(qi>>1)+1
#define UNITS (UNITS_PER_B * B_)

typedef __bf16 bf16_t;
typedef __bf16 bf16x4 __attribute__((ext_vector_type(4)));
typedef __bf16 bf16x8 __attribute__((ext_vector_type(8)));
typedef float f32x4 __attribute__((ext_vector_type(4)));

// ---------------------------------------------------------------------------
// Kernel 0: precast, XCD-aligned. grid 256, block 256.
// Block o (swizzled) converts X rows [swz*32, swz*32+32) -> Xb (bf16), so the
// XCD that later projects those rows finds them dirty in its own L2.
// Also converts W -> Wb and fills the RoPE cos/sin table.
// ---------------------------------------------------------------------------
__global__ __launch_bounds__(256) void precast_kernel(
    const float* __restrict__ X, const float* __restrict__ Wq,
    const float* __restrict__ Wk, const float* __restrict__ Wv,
    bf16_t* __restrict__ Xb, bf16_t* __restrict__ Wb,
    float2* __restrict__ Tab) {
  const int o = blockIdx.x;
  const int swz = (o & 7) * 32 + (o >> 3);   // bijective on [0,256)
  const int r0 = swz * 32;
  const int tid = threadIdx.x;

#pragma unroll 4
  for (int i = 0; i < 16; i++) {
    const int c = tid + i * 256;             // 0..4095 chunks of 8
    const int row = r0 + (c >> 7);
    const int ch = (c & 127) * 8;
    const float* src = X + (size_t)row * E_ + ch;
    float4 u = *(const float4*)src;
    float4 v = *(const float4*)(src + 4);
    bf16x8 t;
    t[0] = (bf16_t)u.x; t[1] = (bf16_t)u.y; t[2] = (bf16_t)u.z; t[3] = (bf16_t)u.w;
    t[4] = (bf16_t)v.x; t[5] = (bf16_t)v.y; t[6] = (bf16_t)v.z; t[7] = (bf16_t)v.w;
    *(bf16x8*)(Xb + (size_t)row * E_ + ch) = t;
  }

  const int gidx = o * 256 + tid;            // 0..65535
  if (gidx < 3 * D_ * E_ / 8) {              // 49152 W chunks
    const int z = gidx / 16384;
    const int r = gidx % 16384;
    const float* src = ((z == 0) ? Wq : (z == 1) ? Wk : Wv) + (size_t)r * 8;
    float4 u = *(const float4*)src;
    float4 v = *(const float4*)(src + 4);
    bf16x8 t;
    t[0] = (bf16_t)u.x; t[1] = (bf16_t)u.y; t[2] = (bf16_t)u.z; t[3] = (bf16_t)u.w;
    t[4] = (bf16_t)v.x; t[5] = (bf16_t)v.y; t[6] = (bf16_t)v.z; t[7] = (bf16_t)v.w;
    *(bf16x8*)(Wb + (size_t)z * D_ * E_ + (size_t)r * 8) = t;
  }

  const float NLOG_ = -0.14391156514261485f;  // -ln(10000)/64
  for (int idx = gidx; idx < T_ * 64; idx += 65536) {
    const int t = idx >> 6, j = idx & 63;
    const float freq = expf(NLOG_ * (float)j);
    float sn, cs;
    sincosf((float)t * freq, &sn, &cs);
    Tab[idx] = make_float2(cs, sn);
  }
}

// ---------------------------------------------------------------------------
// Kernel 1: LDS-free proj GEMM + table RoPE. grid 256, block 256 (4 waves).
// Wave w owns output tile rows [mb*64, mb*64+64) x cols [cb*48, cb*48+48)
// of the fused q|k|v N=384. A/B frags read directly from L2 (no LDS, no
// barriers); 2-deep named-register pipeline, 12 MFMA per 7 loads.
// ---------------------------------------------------------------------------
__global__ __launch_bounds__(256) void proj_lf_kernel(
    const bf16_t* __restrict__ Xb, const bf16_t* __restrict__ Wb,
    const float2* __restrict__ Tab, bf16_t* __restrict__ Qws,
    bf16_t* __restrict__ Kws, bf16_t* __restrict__ Vtws) {
  const int o = blockIdx.x;
  const int swz = (o & 7) * 32 + (o >> 3);   // XCD-chunk: XCD x -> mb 16x..16x+15
  const int wv = threadIdx.x >> 6;
  const int w = swz * 4 + wv;                // 0..1023
  const int mb = w >> 3;                     // 0..127
  const int cbnd = w & 7;                    // 0..7
  const int m0 = mb * 64;
  const int c0 = cbnd * 48;
  const int lane = threadIdx.x & 63;
  const int g = lane >> 4, lm = lane & 15;

  const bf16_t* aP = Xb + (size_t)(m0 + lm) * E_ + g * 8;
  const bf16_t* bP = Wb + (size_t)(c0 + lm) * E_ + g * 8;

  f32x4 acc[4][3];
#pragma unroll
  for (int mf = 0; mf < 4; mf++)
#pragma unroll
    for (int nf = 0; nf < 3; nf++) acc[mf][nf] = 0.0f;

  bf16x8 aA[4], bA[3], aB[4], bB[3];
#pragma unroll
  for (int mf = 0; mf < 4; mf++) aA[mf] = *(const bf16x8*)(aP + mf * 16 * E_);
#pragma unroll
  for (int nf = 0; nf < 3; nf++) bA[nf] = *(const bf16x8*)(bP + nf * 16 * E_);

  for (int kk = 0; kk < 32; kk += 2) {
    const int off1 = (kk + 1) * 32;
#pragma unroll
    for (int mf = 0; mf < 4; mf++)
      aB[mf] = *(const bf16x8*)(aP + mf * 16 * E_ + off1);
#pragma unroll
    for (int nf = 0; nf < 3; nf++)
      bB[nf] = *(const bf16x8*)(bP + nf * 16 * E_ + off1);
#pragma unroll
    for (int mf = 0; mf < 4; mf++)
#pragma unroll
      for (int nf = 0; nf < 3; nf++)
        acc[mf][nf] =
            __builtin_amdgcn_mfma_f32_16x16x32_bf16(aA[mf], bA[nf], acc[mf][nf], 0, 0, 0);
    if (kk + 2 < 32) {
      const int off2 = (kk + 2) * 32;
#pragma unroll
      for (int mf = 0; mf < 4; mf++)
        aA[mf] = *(const bf16x8*)(aP + mf * 16 * E_ + off2);
#pragma unroll
      for (int nf = 0; nf < 3; nf++)
        bA[nf] = *(const bf16x8*)(bP + nf * 16 * E_ + off2);
    }
#pragma unroll
    for (int mf = 0; mf < 4; mf++)
#pragma unroll
      for (int nf = 0; nf < 3; nf++)
        acc[mf][nf] =
            __builtin_amdgcn_mfma_f32_16x16x32_bf16(aB[mf], bB[nf], acc[mf][nf], 0, 0, 0);
  }

  // Epilogue: frag (mf,nf): row = m0+mf*16+g*4+r, col = c0+nf*16+lm.
  const int b = m0 >> 11;
#pragma unroll
  for (int nf = 0; nf < 3; nf++) {
    const int col = c0 + nf * 16 + lm;
    const int z = col >> 7;
    const int d = col & 127;
#pragma unroll
    for (int mf = 0; mf < 4; mf++) {
      const int row0 = m0 + mf * 16 + g * 4;
      if (z < 2) {
        bf16_t* dst = (z == 0) ? Qws : Kws;
#pragma unroll
        for (int r = 0; r < 4; r++) {
          const int bt = row0 + r;
          const int tt = bt & (T_ - 1);
          float val = acc[mf][nf][r];
          float prt = __shfl_xor(val, 1, 64);
          const float2 cs = Tab[(size_t)tt * 64 + (d >> 1)];
          const float outv =
              (d & 1) ? (prt * cs.y + val * cs.x) : (val * cs.x - prt * cs.y);
          dst[(size_t)bt * D_ + d] = (bf16_t)outv;
        }
      } else {
        bf16x4 pv;
#pragma unroll
        for (int r = 0; r < 4; r++) pv[r] = (bf16_t)acc[mf][nf][r];
        const int tt0 = row0 & (T_ - 1);
        *(bf16x4*)&Vtws[((size_t)(b * D_ + d)) * T_ + tt0] = pv;
      }
    }
  }
}

// ---------------------------------------------------------------------------
// Kernel 2a: KV-split causal flash attention partials (R7, T14 async-stage).
// ---------------------------------------------------------------------------
__global__ __launch_bounds__(128) void attn_part_kernel(
    const bf16_t* __restrict__ Qws, const bf16_t* __restrict__ Kws,
    const bf16_t* __restrict__ Vtws, float* __restrict__ Opart,
    float* __restrict__ Mpart, float* __restrict__ Lpart) {
  const int idx = blockIdx.x;
  const int b = idx / UNITS_PER_B;
  const int rem = idx % UNITS_PER_B;
  int qi, ci;
  if (rem < 16) { qi = rem; ci = 0; }
  else if (rem < 48) { int r2 = rem - 16; qi = 16 + (r2 >> 1); ci = r2 & 1; }
  else if (rem < 96) { int r2 = rem - 48; qi = 32 + r2 / 3; ci = r2 % 3; }
  else { int r2 = rem - 96; qi = 48 + (r2 >> 2); ci = r2 & 3; }
  const int slot = idx;

  const int q0 = qi * 32;
  const int tiles = (qi >> 1) + 1;
  const int t0 = ci * 8;
  const int t1 = min(t0 + 8, tiles);

  const int tid = threadIdx.x;
  const int lane = tid & 63;
  const int wv = tid >> 6;
  const int g = lane >> 4;
  const int lm = lane & 15;

  __shared__ bf16_t Ks[64 * 136];
  __shared__ bf16_t Vts[128 * 72];
  __shared__ bf16_t Ps[2 * 16 * 72];

  bf16x8 qf[4];
  {
    const bf16_t* qb = Qws + (size_t)(b * T_ + q0 + wv * 16 + lm) * D_;
#pragma unroll
    for (int kc = 0; kc < 4; kc++) qf[kc] = *(const bf16x8*)(qb + kc * 32 + g * 8);
  }

  f32x4 o[8];
#pragma unroll
  for (int i = 0; i < 8; i++) o[i] = 0.0f;
  float m_r[4], l_r[4];
#pragma unroll
  for (int r = 0; r < 4; r++) { m_r[r] = -1e30f; l_r[r] = 0.0f; }
  const float sc = 0.08838834764831845f;

  bf16x8 kreg[8], vreg[8];
  auto load_tiles = [&](int it) {
    const int k0 = it * 64;
#pragma unroll
    for (int i = 0; i < 8; i++) {
      const int c = tid + i * 128;
      kreg[i] = *(const bf16x8*)(Kws + (size_t)(b * T_ + k0 + (c >> 4)) * D_ +
                                 (c & 15) * 8);
    }
#pragma unroll
    for (int i = 0; i < 8; i++) {
      const int c = tid + i * 128;
      vreg[i] = *(const bf16x8*)(Vtws + (size_t)(b * D_ + (c >> 3)) * T_ + k0 +
                                 (c & 7) * 8);
    }
  };
  auto write_lds = [&]() {
#pragma unroll
    for (int i = 0; i < 8; i++) {
      const int c = tid + i * 128;
      *(bf16x8*)&Ks[(c >> 4) * 136 + (c & 15) * 8] = kreg[i];
    }
#pragma unroll
    for (int i = 0; i < 8; i++) {
      const int c = tid + i * 128;
      *(bf16x8*)&Vts[(c >> 3) * 72 + (c & 7) * 8] = vreg[i];
    }
  };

  load_tiles(t0);
  for (int it = t0; it < t1; it++) {
    write_lds();
    __syncthreads();
    if (it + 1 < t1) load_tiles(it + 1);   // overlaps with compute below

    const int k0 = it * 64;
    f32x4 s[4];
#pragma unroll
    for (int nb = 0; nb < 4; nb++) s[nb] = 0.0f;
#pragma unroll
    for (int nb = 0; nb < 4; nb++) {
#pragma unroll
      for (int kc = 0; kc < 4; kc++) {
        bf16x8 bk = *(const bf16x8*)&Ks[(nb * 16 + lm) * 136 + kc * 32 + g * 8];
        s[nb] = __builtin_amdgcn_mfma_f32_16x16x32_bf16(qf[kc], bk, s[nb], 0, 0, 0);
      }
    }

    const bool diag = (it == tiles - 1);
#pragma unroll
    for (int r = 0; r < 4; r++) {
      const int qrow = q0 + wv * 16 + g * 4 + r;
      float sv[4];
#pragma unroll
      for (int nb = 0; nb < 4; nb++) {
        sv[nb] = s[nb][r] * sc;
        if (diag && (k0 + nb * 16 + lm > qrow)) sv[nb] = -1e30f;
      }
      float tm = fmaxf(fmaxf(sv[0], sv[1]), fmaxf(sv[2], sv[3]));
      tm = fmaxf(tm, __shfl_xor(tm, 1, 64));
      tm = fmaxf(tm, __shfl_xor(tm, 2, 64));
      tm = fmaxf(tm, __shfl_xor(tm, 4, 64));
      tm = fmaxf(tm, __shfl_xor(tm, 8, 64));
      const float mnew = fmaxf(m_r[r], tm);
      const float alpha = __expf(m_r[r] - mnew);
      float p[4], rs = 0.0f;
#pragma unroll
      for (int nb = 0; nb < 4; nb++) { p[nb] = __expf(sv[nb] - mnew); rs += p[nb]; }
      rs += __shfl_xor(rs, 1, 64);
      rs += __shfl_xor(rs, 2, 64);
      rs += __shfl_xor(rs, 4, 64);
      rs += __shfl_xor(rs, 8, 64);
      l_r[r] = l_r[r] * alpha + rs;
      m_r[r] = mnew;
#pragma unroll
      for (int nb2 = 0; nb2 < 8; nb2++) o[nb2][r] *= alpha;
#pragma unroll
      for (int nb = 0; nb < 4; nb++)
        Ps[wv * 1152 + (g * 4 + r) * 72 + nb * 16 + lm] = (bf16_t)p[nb];
    }

    bf16x8 pa0 = *(const bf16x8*)&Ps[wv * 1152 + lm * 72 + g * 8];
    bf16x8 pa1 = *(const bf16x8*)&Ps[wv * 1152 + lm * 72 + 32 + g * 8];
#pragma unroll
    for (int nb2 = 0; nb2 < 8; nb2++) {
      bf16x8 bv0 = *(const bf16x8*)&Vts[(nb2 * 16 + lm) * 72 + g * 8];
      o[nb2] = __builtin_amdgcn_mfma_f32_16x16x32_bf16(pa0, bv0, o[nb2], 0, 0, 0);
      bf16x8 bv1 = *(const bf16x8*)&Vts[(nb2 * 16 + lm) * 72 + 32 + g * 8];
      o[nb2] = __builtin_amdgcn_mfma_f32_16x16x32_bf16(pa1, bv1, o[nb2], 0, 0, 0);
    }
    __syncthreads();
  }

#pragma unroll
  for (int r = 0; r < 4; r++) {
    const int row = wv * 16 + g * 4 + r;
    if (lm == 0) {
      Mpart[slot * 32 + row] = m_r[r];
      Lpart[slot * 32 + row] = l_r[r];
    }
    float* dst = Opart + ((size_t)slot * 32 + row) * D_;
#pragma unroll
    for (int nb2 = 0; nb2 < 8; nb2++) dst[nb2 * 16 + lm] = o[nb2][r];
  }
}

// ---------------------------------------------------------------------------
// Kernel 2b: combine partials. grid (T/32, B), block 256. (unchanged)
// ---------------------------------------------------------------------------
__global__ __launch_bounds__(256) void attn_combine_kernel(
    const float* __restrict__ Opart, const float* __restrict__ Mpart,
    const float* __restrict__ Lpart, float* __restrict__ Out) {
  const int qi = blockIdx.x;
  const int b = blockIdx.y;
  const int gg = qi >> 4;
  const int nc = gg + 1;
  const int base = b * UNITS_PER_B + ((gg * (gg + 1)) / 2) * 16 + (qi & 15) * nc;
  const int t = threadIdx.x;
  const int row = t >> 3;
  const int d0 = (t & 7) * 16;

  float mv[4];
  float mmax = -1e30f;
  for (int ci = 0; ci < nc; ci++) {
    mv[ci] = Mpart[(base + ci) * 32 + row];
    mmax = fmaxf(mmax, mv[ci]);
  }
  f32x4 acc[4];
#pragma unroll
  for (int j = 0; j < 4; j++) acc[j] = 0.0f;
  float l = 0.0f;
  for (int ci = 0; ci < nc; ci++) {
    const float w = __expf(mv[ci] - mmax);
    l += w * Lpart[(base + ci) * 32 + row];
    const float* op = Opart + ((size_t)(base + ci) * 32 + row) * D_ + d0;
#pragma unroll
    for (int j = 0; j < 4; j++) {
      float4 v = *(const float4*)(op + j * 4);
      acc[j][0] += w * v.x; acc[j][1] += w * v.y;
      acc[j][2] += w * v.z; acc[j][3] += w * v.w;
    }
  }
  const float inv = 1.0f / l;
  float* dst = Out + ((size_t)(b * T_ + qi * 32 + row)) * D_ + d0;
#pragma unroll
  for (int j = 0; j < 4; j++) {
    float4 v;
    v.x = acc[j][0] * inv; v.y = acc[j][1] * inv;
    v.z = acc[j][2] * inv; v.w = acc[j][3] * inv;
    *(float4*)(dst + j * 4) = v;
  }
}

// ---------------------------------------------------------------------------
// Fallback proj (round-1): direct f32 inputs, M64 tile. grid (BT/64,3), 256.
// ---------------------------------------------------------------------------
__global__ __launch_bounds__(256) void proj_rope_kernel(
    const float* __restrict__ X, const float* __restrict__ Wq,
    const float* __restrict__ Wk, const float* __restrict__ Wv,
    bf16_t* __restrict__ Qws, bf16_t* __restrict__ Kws,
    bf16_t* __restrict__ Vtws) {
  const int z = blockIdx.y;
  const float* __restrict__ W = (z == 0) ? Wq : (z == 1) ? Wk : Wv;
  const int bt0 = blockIdx.x * 64;
  const int tid = threadIdx.x;
  const int lane = tid & 63;
  const int wv = tid >> 6;
  const int g = lane >> 4;
  const int lm = lane & 15;

  __shared__ bf16_t Xs[64 * 40];
  __shared__ bf16_t Ws[128 * 40];

  f32x4 acc[8];
#pragma unroll
  for (int i = 0; i < 8; i++) acc[i] = 0.0f;

  for (int kk = 0; kk < E_ / 32; kk++) {
    {
      const int row = tid >> 2, c0 = (tid & 3) * 8;
      const float* src = X + (size_t)(bt0 + row) * E_ + kk * 32 + c0;
      float4 u = *(const float4*)src;
      float4 v = *(const float4*)(src + 4);
      bf16x8 t;
      t[0] = (bf16_t)u.x; t[1] = (bf16_t)u.y; t[2] = (bf16_t)u.z; t[3] = (bf16_t)u.w;
      t[4] = (bf16_t)v.x; t[5] = (bf16_t)v.y; t[6] = (bf16_t)v.z; t[7] = (bf16_t)v.w;
      *(bf16x8*)&Xs[row * 40 + c0] = t;
    }
#pragma unroll
    for (int h = 0; h < 2; h++) {
      const int cc = tid * 2 + h;
      const int row = cc >> 2, c0 = (cc & 3) * 8;
      const float* src = W + (size_t)row * E_ + kk * 32 + c0;
      float4 u = *(const float4*)src;
      float4 v = *(const float4*)(src + 4);
      bf16x8 t;
      t[0] = (bf16_t)u.x; t[1] = (bf16_t)u.y; t[2] = (bf16_t)u.z; t[3] = (bf16_t)u.w;
      t[4] = (bf16_t)v.x; t[5] = (bf16_t)v.y; t[6] = (bf16_t)v.z; t[7] = (bf16_t)v.w;
      *(bf16x8*)&Ws[row * 40 + c0] = t;
    }
    __syncthreads();
    bf16x8 a = *(const bf16x8*)&Xs[(wv * 16 + lm) * 40 + g * 8];
#pragma unroll
    for (int nb = 0; nb < 8; nb++) {
      bf16x8 bb = *(const bf16x8*)&Ws[(nb * 16 + lm) * 40 + g * 8];
      acc[nb] = __builtin_amdgcn_mfma_f32_16x16x32_bf16(a, bb, acc[nb], 0, 0, 0);
    }
    __syncthreads();
  }
  const float NLOG_ = -0.14391156514261485f;
#pragma unroll
  for (int nb = 0; nb < 8; nb++) {
    const int col = nb * 16 + lm;
    const float freq = expf(NLOG_ * (float)(col >> 1));
#pragma unroll
    for (int r = 0; r < 4; r++) {
      const int bt = bt0 + wv * 16 + g * 4 + r;
      float val = acc[nb][r];
      float prt = __shfl_xor(val, 1, 64);
      if (z < 2) {
        const int t = bt & (T_ - 1);
        const float ang = (float)t * freq;
        float sn, cs;
        sincosf(ang, &sn, &cs);
        const float outv = (col & 1) ? (prt * sn + val * cs) : (val * cs - prt * sn);
        bf16_t* dst = (z == 0) ? Qws : Kws;
        dst[(size_t)bt * D_ + col] = (bf16_t)outv;
      } else {
        const int b = bt >> 11, t = bt & (T_ - 1);
        Vtws[((size_t)(b * D_ + col)) * T_ + t] = (bf16_t)val;
      }
    }
  }
}

// ---------------------------------------------------------------------------
// Fallback: single-pass flash attention (round-1 kernel)
// ---------------------------------------------------------------------------
__global__ __launch_bounds__(128) void attn_kernel(
    const bf16_t* __restrict__ Qws, const bf16_t* __restrict__ Kws,
    const bf16_t* __restrict__ Vtws, float* __restrict__ Out) {
  const int b = blockIdx.y;
  const int qi = blockIdx.x;
  const int q0 = qi * 32;
  const int tid = threadIdx.x;
  const int lane = tid & 63;
  const int wv = tid >> 6;
  const int g = lane >> 4;
  const int lm = lane & 15;

  __shared__ bf16_t Ks[32 * 136];
  __shared__ bf16_t Vts[128 * 40];
  __shared__ bf16_t Ps[2 * 16 * 40];

  bf16x8 qf[4];
  {
    const bf16_t* qb = Qws + (size_t)(b * T_ + q0 + wv * 16 + lm) * D_;
#pragma unroll
    for (int kk = 0; kk < 4; kk++) qf[kk] = *(const bf16x8*)(qb + kk * 32 + g * 8);
  }
  f32x4 o[8];
#pragma unroll
  for (int i = 0; i < 8; i++) o[i] = 0.0f;
  float m_r[4], l_r[4];
#pragma unroll
  for (int r = 0; r < 4; r++) { m_r[r] = -1e30f; l_r[r] = 0.0f; }
  const float sc = 0.08838834764831845f;

  for (int kt = 0; kt <= qi; kt++) {
    const int kv0 = kt * 32;
#pragma unroll
    for (int i = 0; i < 4; i++) {
      const int c = tid + i * 128;
      const int row = c >> 4, part = c & 15;
      bf16x8 v = *(const bf16x8*)(Kws + (size_t)(b * T_ + kv0 + row) * D_ + part * 8);
      *(bf16x8*)&Ks[row * 136 + part * 8] = v;
    }
#pragma unroll
    for (int i = 0; i < 4; i++) {
      const int c = tid + i * 128;
      const int d = c >> 2, part = c & 3;
      bf16x8 v = *(const bf16x8*)(Vtws + (size_t)(b * D_ + d) * T_ + kv0 + part * 8);
      *(bf16x8*)&Vts[d * 40 + part * 8] = v;
    }
    __syncthreads();
    f32x4 s[2];
    s[0] = 0.0f; s[1] = 0.0f;
#pragma unroll
    for (int nb = 0; nb < 2; nb++) {
#pragma unroll
      for (int kc = 0; kc < 4; kc++) {
        bf16x8 bk = *(const bf16x8*)&Ks[(nb * 16 + lm) * 136 + kc * 32 + g * 8];
        s[nb] = __builtin_amdgcn_mfma_f32_16x16x32_bf16(qf[kc], bk, s[nb], 0, 0, 0);
      }
    }
    const bool diag = (kt == qi);
#pragma unroll
    for (int r = 0; r < 4; r++) {
      float sv0 = s[0][r] * sc;
      float sv1 = s[1][r] * sc;
      if (diag) {
        const int rowr = wv * 16 + g * 4 + r;
        if (lm > rowr) sv0 = -1e30f;
        if (lm + 16 > rowr) sv1 = -1e30f;
      }
      float tm = fmaxf(sv0, sv1);
      tm = fmaxf(tm, __shfl_xor(tm, 1, 64));
      tm = fmaxf(tm, __shfl_xor(tm, 2, 64));
      tm = fmaxf(tm, __shfl_xor(tm, 4, 64));
      tm = fmaxf(tm, __shfl_xor(tm, 8, 64));
      const float mnew = fmaxf(m_r[r], tm);
      const float alpha = __expf(m_r[r] - mnew);
      const float p0 = __expf(sv0 - mnew);
      const float p1 = __expf(sv1 - mnew);
      float rs = p0 + p1;
      rs += __shfl_xor(rs, 1, 64);
      rs += __shfl_xor(rs, 2, 64);
      rs += __shfl_xor(rs, 4, 64);
      rs += __shfl_xor(rs, 8, 64);
      l_r[r] = l_r[r] * alpha + rs;
      m_r[r] = mnew;
#pragma unroll
      for (int nb2 = 0; nb2 < 8; nb2++) o[nb2][r] *= alpha;
      Ps[wv * 640 + (g * 4 + r) * 40 + lm] = (bf16_t)p0;
      Ps[wv * 640 + (g * 4 + r) * 40 + 16 + lm] = (bf16_t)p1;
    }
    bf16x8 pa = *(const bf16x8*)&Ps[wv * 640 + lm * 40 + g * 8];
#pragma unroll
    for (int nb2 = 0; nb2 < 8; nb2++) {
      bf16x8 bv = *(const bf16x8*)&Vts[(nb2 * 16 + lm) * 40 + g * 8];
      o[nb2] = __builtin_amdgcn_mfma_f32_16x16x32_bf16(pa, bv, o[nb2], 0, 0, 0);
    }
    __syncthreads();
  }
#pragma unroll
  for (int r = 0; r < 4; r++) {
    const float inv = 1.0f / l_r[r];
    float* dst = Out + (size_t)(b * T_ + q0 + wv * 16 + g * 4 + r) * D_;
#pragma unroll
    for (int nb2 = 0; nb2 < 8; nb2++) dst[nb2 * 16 + lm] = o[nb2][r] * inv;
  }
}

extern "C" void kernel_launch(void* const* d_in, const int* in_sizes, int n_in,
                              void* d_out, int out_size, void* d_ws,
                              size_t ws_size, hipStream_t stream) {
  const float* X = (const float*)d_in[0];
  const float* Wq = (const float*)d_in[1];
  const float* Wk = (const float*)d_in[2];
  const float* Wv = (const float*)d_in[3];
  float* Out = (float*)d_out;

  const size_t xb_bytes = (size_t)BT_ * E_ * sizeof(bf16_t);       // 16 MB
  const size_t wb_bytes = (size_t)3 * D_ * E_ * sizeof(bf16_t);    // 0.75 MB
  const size_t qkv_bytes = (size_t)3 * BT_ * D_ * sizeof(bf16_t);  // 6 MB
  const size_t opart_bytes = (size_t)UNITS * 32 * D_ * sizeof(float);  // 10 MB
  const size_t ml_bytes = (size_t)UNITS * 32 * sizeof(float);
  const size_t tab_bytes = (size_t)T_ * 64 * sizeof(float2);       // 1 MB

  const size_t needA =
      xb_bytes + wb_bytes + qkv_bytes + opart_bytes + 2 * ml_bytes + tab_bytes;
  const size_t needB = qkv_bytes + opart_bytes + 2 * ml_bytes;

  if (ws_size >= needA) {
    bf16_t* Xb = (bf16_t*)d_ws;
    bf16_t* Wb = Xb + (size_t)BT_ * E_;
    bf16_t* Qws = Wb + (size_t)3 * D_ * E_;
    bf16_t* Kws = Qws + (size_t)BT_ * D_;
    bf16_t* Vtws = Kws + (size_t)BT_ * D_;
    float* Opart = (float*)((char*)d_ws + xb_bytes + wb_bytes + qkv_bytes);
    float* Mpart = (float*)((char*)Opart + opart_bytes);
    float* Lpart = (float*)((char*)Mpart + ml_bytes);
    float2* Tab = (float2*)((char*)Lpart + ml_bytes);

    hipLaunchKernelGGL(precast_kernel, dim3(256), dim3(256), 0, stream,
                       X, Wq, Wk, Wv, Xb, Wb, Tab);
    hipLaunchKernelGGL(proj_lf_kernel, dim3(256), dim3(256), 0, stream,
                       Xb, Wb, Tab, Qws, Kws, Vtws);
    hipLaunchKernelGGL(attn_part_kernel, dim3(UNITS), dim3(128), 0, stream,
                       Qws, Kws, Vtws, Opart, Mpart, Lpart);
    hipLaunchKernelGGL(attn_combine_kernel, dim3(T_ / 32, B_), dim3(256), 0,
                       stream, Opart, Mpart, Lpart, Out);
  } else if (ws_size >= needB) {
    bf16_t* Qws = (bf16_t*)d_ws;
    bf16_t* Kws = Qws + (size_t)BT_ * D_;
    bf16_t* Vtws = Kws + (size_t)BT_ * D_;
    float* Opart = (float*)((char*)d_ws + qkv_bytes);
    float* Mpart = (float*)((char*)Opart + opart_bytes);
    float* Lpart = (float*)((char*)Mpart + ml_bytes);
    hipLaunchKernelGGL(proj_rope_kernel, dim3(BT_ / 64, 3), dim3(256), 0,
                       stream, X, Wq, Wk, Wv, Qws, Kws, Vtws);
    hipLaunchKernelGGL(attn_part_kernel, dim3(UNITS), dim3(128), 0, stream,
                       Qws, Kws, Vtws, Opart, Mpart, Lpart);
    hipLaunchKernelGGL(attn_combine_kernel, dim3(T_ / 32, B_), dim3(256), 0,
                       stream, Opart, Mpart, Lpart, Out);
  } else {
    bf16_t* Qws = (bf16_t*)d_ws;
    bf16_t* Kws = Qws + (size_t)BT_ * D_;
    bf16_t* Vtws = Kws + (size_t)BT_ * D_;
    hipLaunchKernelGGL(proj_rope_kernel, dim3(BT_ / 64, 3), dim3(256), 0,
                       stream, X, Wq, Wk, Wv, Qws, Kws, Vtws);
    hipLaunchKernelGGL(attn_kernel, dim3(T_ / 32, B_), dim3(128), 0, stream,
                       Qws, Kws, Vtws, Out);
  }
}

// Round 9
// 76.871 us; speedup vs baseline: 1.0033x; 1.0033x over previous
//
#include <hip/hip_runtime.h>
#include <math.h>

// CausalAttention: q/k/v = X @ W^T, RoPE(q,k), flash causal attention.
// B=4 T=2048 E=1024 D=128, f32 in/out, bf16 MFMA internally.
// Round 9: W-stationary-LDS proj. Each block: one 48-col W band converted
// f32->bf16 into 96KB LDS once (XOR-swizzle, 2-way conflicts = free), then a
// BARRIER-FREE main loop: 8 waves stream X rows as f32 straight from HBM/L2
// (precast kernel eliminated), cvt in-register, MFMA vs LDS W. XCD-chunked
// (8 bands of one m-range share an XCD -> X slice L2-resident).

#define B_ 4
#define T_ 2048
#define E_ 1024
#define D_ 128
#define BT_ (B_ * T_)

#define UNITS_PER_B 160   // sum over qi of ceil(tiles(qi)/8), tiles(qi)=(qi>>1)+1
#define UNITS (UNITS_PER_B * B_)

typedef __bf16 bf16_t;
typedef __bf16 bf16x4 __attribute__((ext_vector_type(4)));
typedef __bf16 bf16x8 __attribute__((ext_vector_type(8)));
typedef float f32x4 __attribute__((ext_vector_type(4)));

__device__ __forceinline__ bf16x8 cvt8(float4 lo, float4 hi) {
  bf16x8 t;
  t[0] = (bf16_t)lo.x; t[1] = (bf16_t)lo.y; t[2] = (bf16_t)lo.z; t[3] = (bf16_t)lo.w;
  t[4] = (bf16_t)hi.x; t[5] = (bf16_t)hi.y; t[6] = (bf16_t)hi.z; t[7] = (bf16_t)hi.w;
  return t;
}

// ---------------------------------------------------------------------------
// Kernel 0: RoPE table only. Tab[t][j] = (cos, sin). grid 512, block 256.
// ---------------------------------------------------------------------------
__global__ __launch_bounds__(256) void tab_kernel(float2* __restrict__ Tab) {
  const int idx = blockIdx.x * 256 + threadIdx.x;  // T*64 = 131072 entries
  const int t = idx >> 6, j = idx & 63;
  const float NLOG_ = -0.14391156514261485f;  // -ln(10000)/64
  const float freq = expf(NLOG_ * (float)j);
  float sn, cs;
  sincosf((float)t * freq, &sn, &cs);
  Tab[idx] = make_float2(cs, sn);
}

// ---------------------------------------------------------------------------
// Kernel 1: W-stationary proj + table RoPE. grid 256, block 512 (8 waves).
// Block o: band=(o>>3)&7 (48 cols of fused q|k|v), mgrp=(o&7)*4+(o>>6)
// (256 rows). XCD o&7 owns rows [xcd*1024,(xcd+1)*1024) for all 8 bands.
// Wave wv: rows m0+wv*32..+32 (2 m-frags) x 48 cols (3 n-frags).
// ---------------------------------------------------------------------------
__global__ __launch_bounds__(512, 1) void proj_wlds_kernel(
    const float* __restrict__ X, const float* __restrict__ Wq,
    const float* __restrict__ Wk, const float* __restrict__ Wv,
    const float2* __restrict__ Tab, bf16_t* __restrict__ Qws,
    bf16_t* __restrict__ Kws, bf16_t* __restrict__ Vtws) {
  const int o = blockIdx.x;
  const int band = (o >> 3) & 7;
  const int mgrp = (o & 7) * 4 + (o >> 6);
  const int m0 = mgrp * 256;
  const int c0 = band * 48;

  const int tid = threadIdx.x;
  const int lane = tid & 63;
  const int wv = tid >> 6;              // 0..7
  const int g = lane >> 4, lm = lane & 15;

  __shared__ bf16_t Wl[48 * 1024];      // 96 KB, XOR-swizzled rows

  // ---- one-time W band load: f32 -> bf16 -> swizzled LDS ----
#pragma unroll
  for (int i = 0; i < 12; i++) {
    const int c = tid + i * 512;        // 0..6143 chunks of 8
    const int row = c >> 7;             // 0..47 (band-local col)
    const int ch = c & 127;             // k-chunk of 8
    const int col = c0 + row;
    const int z = col >> 7, d = col & 127;
    const float* src =
        ((z == 0) ? Wq : (z == 1) ? Wk : Wv) + (size_t)d * E_ + ch * 8;
    float4 u = *(const float4*)src;
    float4 v = *(const float4*)(src + 4);
    const int eoff = (ch * 8) ^ ((row & 7) << 3);
    *(bf16x8*)&Wl[row * 1024 + eoff] = cvt8(u, v);
  }
  __syncthreads();                      // the ONLY block barrier

  // ---- barrier-free main loop ----
  const int r0 = m0 + wv * 32;
  const float* xrow0 = X + (size_t)(r0 + lm) * E_ + g * 8;
  const float* xrow1 = X + (size_t)(r0 + 16 + lm) * E_ + g * 8;

  f32x4 acc[2][3];
#pragma unroll
  for (int mf = 0; mf < 2; mf++)
#pragma unroll
    for (int nf = 0; nf < 3; nf++) acc[mf][nf] = 0.0f;

#pragma unroll 4
  for (int kk = 0; kk < 32; kk++) {
    const int xo = kk * 32;
    float4 a0lo = *(const float4*)(xrow0 + xo);
    float4 a0hi = *(const float4*)(xrow0 + xo + 4);
    float4 a1lo = *(const float4*)(xrow1 + xo);
    float4 a1hi = *(const float4*)(xrow1 + xo + 4);
    bf16x8 a0 = cvt8(a0lo, a0hi);
    bf16x8 a1 = cvt8(a1lo, a1hi);
    const int bko = kk * 32 + g * 8;
#pragma unroll
    for (int nf = 0; nf < 3; nf++) {
      const int row = nf * 16 + lm;
      bf16x8 bb = *(const bf16x8*)&Wl[row * 1024 + (bko ^ ((row & 7) << 3))];
      acc[0][nf] = __builtin_amdgcn_mfma_f32_16x16x32_bf16(a0, bb, acc[0][nf], 0, 0, 0);
      acc[1][nf] = __builtin_amdgcn_mfma_f32_16x16x32_bf16(a1, bb, acc[1][nf], 0, 0, 0);
    }
  }

  // ---- epilogue: frag (mf,nf): row = r0+mf*16+g*4+r, col = c0+nf*16+lm ----
  const int b = r0 >> 11;
#pragma unroll
  for (int nf = 0; nf < 3; nf++) {
    const int col = c0 + nf * 16 + lm;
    const int z = col >> 7;
    const int d = col & 127;
#pragma unroll
    for (int mf = 0; mf < 2; mf++) {
      const int row0 = r0 + mf * 16 + g * 4;
      if (z < 2) {
        bf16_t* dst = (z == 0) ? Qws : Kws;
#pragma unroll
        for (int r = 0; r < 4; r++) {
          const int bt = row0 + r;
          const int tt = bt & (T_ - 1);
          float val = acc[mf][nf][r];
          float prt = __shfl_xor(val, 1, 64);
          const float2 cs = Tab[(size_t)tt * 64 + (d >> 1)];
          const float outv =
              (d & 1) ? (prt * cs.y + val * cs.x) : (val * cs.x - prt * cs.y);
          dst[(size_t)bt * D_ + d] = (bf16_t)outv;
        }
      } else {
        bf16x4 pv;
#pragma unroll
        for (int r = 0; r < 4; r++) pv[r] = (bf16_t)acc[mf][nf][r];
        const int tt0 = row0 & (T_ - 1);
        *(bf16x4*)&Vtws[((size_t)(b * D_ + d)) * T_ + tt0] = pv;
      }
    }
  }
}

// ---------------------------------------------------------------------------
// Kernel 2a: KV-split causal flash attention partials (R7, T14 async-stage).
// ---------------------------------------------------------------------------
__global__ __launch_bounds__(128) void attn_part_kernel(
    const bf16_t* __restrict__ Qws, const bf16_t* __restrict__ Kws,
    const bf16_t* __restrict__ Vtws, float* __restrict__ Opart,
    float* __restrict__ Mpart, float* __restrict__ Lpart) {
  const int idx = blockIdx.x;
  const int b = idx / UNITS_PER_B;
  const int rem = idx % UNITS_PER_B;
  int qi, ci;
  if (rem < 16) { qi = rem; ci = 0; }
  else if (rem < 48) { int r2 = rem - 16; qi = 16 + (r2 >> 1); ci = r2 & 1; }
  else if (rem < 96) { int r2 = rem - 48; qi = 32 + r2 / 3; ci = r2 % 3; }
  else { int r2 = rem - 96; qi = 48 + (r2 >> 2); ci = r2 & 3; }
  const int slot = idx;

  const int q0 = qi * 32;
  const int tiles = (qi >> 1) + 1;
  const int t0 = ci * 8;
  const int t1 = min(t0 + 8, tiles);

  const int tid = threadIdx.x;
  const int lane = tid & 63;
  const int wv = tid >> 6;
  const int g = lane >> 4;
  const int lm = lane & 15;

  __shared__ bf16_t Ks[64 * 136];
  __shared__ bf16_t Vts[128 * 72];
  __shared__ bf16_t Ps[2 * 16 * 72];

  bf16x8 qf[4];
  {
    const bf16_t* qb = Qws + (size_t)(b * T_ + q0 + wv * 16 + lm) * D_;
#pragma unroll
    for (int kc = 0; kc < 4; kc++) qf[kc] = *(const bf16x8*)(qb + kc * 32 + g * 8);
  }

  f32x4 o[8];
#pragma unroll
  for (int i = 0; i < 8; i++) o[i] = 0.0f;
  float m_r[4], l_r[4];
#pragma unroll
  for (int r = 0; r < 4; r++) { m_r[r] = -1e30f; l_r[r] = 0.0f; }
  const float sc = 0.08838834764831845f;

  bf16x8 kreg[8], vreg[8];
  auto load_tiles = [&](int it) {
    const int k0 = it * 64;
#pragma unroll
    for (int i = 0; i < 8; i++) {
      const int c = tid + i * 128;
      kreg[i] = *(const bf16x8*)(Kws + (size_t)(b * T_ + k0 + (c >> 4)) * D_ +
                                 (c & 15) * 8);
    }
#pragma unroll
    for (int i = 0; i < 8; i++) {
      const int c = tid + i * 128;
      vreg[i] = *(const bf16x8*)(Vtws + (size_t)(b * D_ + (c >> 3)) * T_ + k0 +
                                 (c & 7) * 8);
    }
  };
  auto write_lds = [&]() {
#pragma unroll
    for (int i = 0; i < 8; i++) {
      const int c = tid + i * 128;
      *(bf16x8*)&Ks[(c >> 4) * 136 + (c & 15) * 8] = kreg[i];
    }
#pragma unroll
    for (int i = 0; i < 8; i++) {
      const int c = tid + i * 128;
      *(bf16x8*)&Vts[(c >> 3) * 72 + (c & 7) * 8] = vreg[i];
    }
  };

  load_tiles(t0);
  for (int it = t0; it < t1; it++) {
    write_lds();
    __syncthreads();
    if (it + 1 < t1) load_tiles(it + 1);   // overlaps with compute below

    const int k0 = it * 64;
    f32x4 s[4];
#pragma unroll
    for (int nb = 0; nb < 4; nb++) s[nb] = 0.0f;
#pragma unroll
    for (int nb = 0; nb < 4; nb++) {
#pragma unroll
      for (int kc = 0; kc < 4; kc++) {
        bf16x8 bk = *(const bf16x8*)&Ks[(nb * 16 + lm) * 136 + kc * 32 + g * 8];
        s[nb] = __builtin_amdgcn_mfma_f32_16x16x32_bf16(qf[kc], bk, s[nb], 0, 0, 0);
      }
    }

    const bool diag = (it == tiles - 1);
#pragma unroll
    for (int r = 0; r < 4; r++) {
      const int qrow = q0 + wv * 16 + g * 4 + r;
      float sv[4];
#pragma unroll
      for (int nb = 0; nb < 4; nb++) {
        sv[nb] = s[nb][r] * sc;
        if (diag && (k0 + nb * 16 + lm > qrow)) sv[nb] = -1e30f;
      }
      float tm = fmaxf(fmaxf(sv[0], sv[1]), fmaxf(sv[2], sv[3]));
      tm = fmaxf(tm, __shfl_xor(tm, 1, 64));
      tm = fmaxf(tm, __shfl_xor(tm, 2, 64));
      tm = fmaxf(tm, __shfl_xor(tm, 4, 64));
      tm = fmaxf(tm, __shfl_xor(tm, 8, 64));
      const float mnew = fmaxf(m_r[r], tm);
      const float alpha = __expf(m_r[r] - mnew);
      float p[4], rs = 0.0f;
#pragma unroll
      for (int nb = 0; nb < 4; nb++) { p[nb] = __expf(sv[nb] - mnew); rs += p[nb]; }
      rs += __shfl_xor(rs, 1, 64);
      rs += __shfl_xor(rs, 2, 64);
      rs += __shfl_xor(rs, 4, 64);
      rs += __shfl_xor(rs, 8, 64);
      l_r[r] = l_r[r] * alpha + rs;
      m_r[r] = mnew;
#pragma unroll
      for (int nb2 = 0; nb2 < 8; nb2++) o[nb2][r] *= alpha;
#pragma unroll
      for (int nb = 0; nb < 4; nb++)
        Ps[wv * 1152 + (g * 4 + r) * 72 + nb * 16 + lm] = (bf16_t)p[nb];
    }

    bf16x8 pa0 = *(const bf16x8*)&Ps[wv * 1152 + lm * 72 + g * 8];
    bf16x8 pa1 = *(const bf16x8*)&Ps[wv * 1152 + lm * 72 + 32 + g * 8];
#pragma unroll
    for (int nb2 = 0; nb2 < 8; nb2++) {
      bf16x8 bv0 = *(const bf16x8*)&Vts[(nb2 * 16 + lm) * 72 + g * 8];
      o[nb2] = __builtin_amdgcn_mfma_f32_16x16x32_bf16(pa0, bv0, o[nb2], 0, 0, 0);
      bf16x8 bv1 = *(const bf16x8*)&Vts[(nb2 * 16 + lm) * 72 + 32 + g * 8];
      o[nb2] = __builtin_amdgcn_mfma_f32_16x16x32_bf16(pa1, bv1, o[nb2], 0, 0, 0);
    }
    __syncthreads();
  }

#pragma unroll
  for (int r = 0; r < 4; r++) {
    const int row = wv * 16 + g * 4 + r;
    if (lm == 0) {
      Mpart[slot * 32 + row] = m_r[r];
      Lpart[slot * 32 + row] = l_r[r];
    }
    float* dst = Opart + ((size_t)slot * 32 + row) * D_;
#pragma unroll
    for (int nb2 = 0; nb2 < 8; nb2++) dst[nb2 * 16 + lm] = o[nb2][r];
  }
}

// ---------------------------------------------------------------------------
// Kernel 2b: combine partials. grid (T/32, B), block 256. (unchanged)
// ---------------------------------------------------------------------------
__global__ __launch_bounds__(256) void attn_combine_kernel(
    const float* __restrict__ Opart, const float* __restrict__ Mpart,
    const float* __restrict__ Lpart, float* __restrict__ Out) {
  const int qi = blockIdx.x;
  const int b = blockIdx.y;
  const int gg = qi >> 4;
  const int nc = gg + 1;
  const int base = b * UNITS_PER_B + ((gg * (gg + 1)) / 2) * 16 + (qi & 15) * nc;
  const int t = threadIdx.x;
  const int row = t >> 3;
  const int d0 = (t & 7) * 16;

  float mv[4];
  float mmax = -1e30f;
  for (int ci = 0; ci < nc; ci++) {
    mv[ci] = Mpart[(base + ci) * 32 + row];
    mmax = fmaxf(mmax, mv[ci]);
  }
  f32x4 acc[4];
#pragma unroll
  for (int j = 0; j < 4; j++) acc[j] = 0.0f;
  float l = 0.0f;
  for (int ci = 0; ci < nc; ci++) {
    const float w = __expf(mv[ci] - mmax);
    l += w * Lpart[(base + ci) * 32 + row];
    const float* op = Opart + ((size_t)(base + ci) * 32 + row) * D_ + d0;
#pragma unroll
    for (int j = 0; j < 4; j++) {
      float4 v = *(const float4*)(op + j * 4);
      acc[j][0] += w * v.x; acc[j][1] += w * v.y;
      acc[j][2] += w * v.z; acc[j][3] += w * v.w;
    }
  }
  const float inv = 1.0f / l;
  float* dst = Out + ((size_t)(b * T_ + qi * 32 + row)) * D_ + d0;
#pragma unroll
  for (int j = 0; j < 4; j++) {
    float4 v;
    v.x = acc[j][0] * inv; v.y = acc[j][1] * inv;
    v.z = acc[j][2] * inv; v.w = acc[j][3] * inv;
    *(float4*)(dst + j * 4) = v;
  }
}

// ---------------------------------------------------------------------------
// Fallback proj (round-1): direct f32 inputs, M64 tile. grid (BT/64,3), 256.
// ---------------------------------------------------------------------------
__global__ __launch_bounds__(256) void proj_rope_kernel(
    const float* __restrict__ X, const float* __restrict__ Wq,
    const float* __restrict__ Wk, const float* __restrict__ Wv,
    bf16_t* __restrict__ Qws, bf16_t* __restrict__ Kws,
    bf16_t* __restrict__ Vtws) {
  const int z = blockIdx.y;
  const float* __restrict__ W = (z == 0) ? Wq : (z == 1) ? Wk : Wv;
  const int bt0 = blockIdx.x * 64;
  const int tid = threadIdx.x;
  const int lane = tid & 63;
  const int wv = tid >> 6;
  const int g = lane >> 4;
  const int lm = lane & 15;

  __shared__ bf16_t Xs[64 * 40];
  __shared__ bf16_t Ws[128 * 40];

  f32x4 acc[8];
#pragma unroll
  for (int i = 0; i < 8; i++) acc[i] = 0.0f;

  for (int kk = 0; kk < E_ / 32; kk++) {
    {
      const int row = tid >> 2, c0 = (tid & 3) * 8;
      const float* src = X + (size_t)(bt0 + row) * E_ + kk * 32 + c0;
      float4 u = *(const float4*)src;
      float4 v = *(const float4*)(src + 4);
      *(bf16x8*)&Xs[row * 40 + c0] = cvt8(u, v);
    }
#pragma unroll
    for (int h = 0; h < 2; h++) {
      const int cc = tid * 2 + h;
      const int row = cc >> 2, c0 = (cc & 3) * 8;
      const float* src = W + (size_t)row * E_ + kk * 32 + c0;
      float4 u = *(const float4*)src;
      float4 v = *(const float4*)(src + 4);
      *(bf16x8*)&Ws[row * 40 + c0] = cvt8(u, v);
    }
    __syncthreads();
    bf16x8 a = *(const bf16x8*)&Xs[(wv * 16 + lm) * 40 + g * 8];
#pragma unroll
    for (int nb = 0; nb < 8; nb++) {
      bf16x8 bb = *(const bf16x8*)&Ws[(nb * 16 + lm) * 40 + g * 8];
      acc[nb] = __builtin_amdgcn_mfma_f32_16x16x32_bf16(a, bb, acc[nb], 0, 0, 0);
    }
    __syncthreads();
  }
  const float NLOG_ = -0.14391156514261485f;
#pragma unroll
  for (int nb = 0; nb < 8; nb++) {
    const int col = nb * 16 + lm;
    const float freq = expf(NLOG_ * (float)(col >> 1));
#pragma unroll
    for (int r = 0; r < 4; r++) {
      const int bt = bt0 + wv * 16 + g * 4 + r;
      float val = acc[nb][r];
      float prt = __shfl_xor(val, 1, 64);
      if (z < 2) {
        const int t = bt & (T_ - 1);
        const float ang = (float)t * freq;
        float sn, cs;
        sincosf(ang, &sn, &cs);
        const float outv = (col & 1) ? (prt * sn + val * cs) : (val * cs - prt * sn);
        bf16_t* dst = (z == 0) ? Qws : Kws;
        dst[(size_t)bt * D_ + col] = (bf16_t)outv;
      } else {
        const int b = bt >> 11, t = bt & (T_ - 1);
        Vtws[((size_t)(b * D_ + col)) * T_ + t] = (bf16_t)val;
      }
    }
  }
}

// ---------------------------------------------------------------------------
// Fallback: single-pass flash attention (round-1 kernel)
// ---------------------------------------------------------------------------
__global__ __launch_bounds__(128) void attn_kernel(
    const bf16_t* __restrict__ Qws, const bf16_t* __restrict__ Kws,
    const bf16_t* __restrict__ Vtws, float* __restrict__ Out) {
  const int b = blockIdx.y;
  const int qi = blockIdx.x;
  const int q0 = qi * 32;
  const int tid = threadIdx.x;
  const int lane = tid & 63;
  const int wv = tid >> 6;
  const int g = lane >> 4;
  const int lm = lane & 15;

  __shared__ bf16_t Ks[32 * 136];
  __shared__ bf16_t Vts[128 * 40];
  __shared__ bf16_t Ps[2 * 16 * 40];

  bf16x8 qf[4];
  {
    const bf16_t* qb = Qws + (size_t)(b * T_ + q0 + wv * 16 + lm) * D_;
#pragma unroll
    for (int kk = 0; kk < 4; kk++) qf[kk] = *(const bf16x8*)(qb + kk * 32 + g * 8);
  }
  f32x4 o[8];
#pragma unroll
  for (int i = 0; i < 8; i++) o[i] = 0.0f;
  float m_r[4], l_r[4];
#pragma unroll
  for (int r = 0; r < 4; r++) { m_r[r] = -1e30f; l_r[r] = 0.0f; }
  const float sc = 0.08838834764831845f;

  for (int kt = 0; kt <= qi; kt++) {
    const int kv0 = kt * 32;
#pragma unroll
    for (int i = 0; i < 4; i++) {
      const int c = tid + i * 128;
      const int row = c >> 4, part = c & 15;
      bf16x8 v = *(const bf16x8*)(Kws + (size_t)(b * T_ + kv0 + row) * D_ + part * 8);
      *(bf16x8*)&Ks[row * 136 + part * 8] = v;
    }
#pragma unroll
    for (int i = 0; i < 4; i++) {
      const int c = tid + i * 128;
      const int d = c >> 2, part = c & 3;
      bf16x8 v = *(const bf16x8*)(Vtws + (size_t)(b * D_ + d) * T_ + kv0 + part * 8);
      *(bf16x8*)&Vts[d * 40 + part * 8] = v;
    }
    __syncthreads();
    f32x4 s[2];
    s[0] = 0.0f; s[1] = 0.0f;
#pragma unroll
    for (int nb = 0; nb < 2; nb++) {
#pragma unroll
      for (int kc = 0; kc < 4; kc++) {
        bf16x8 bk = *(const bf16x8*)&Ks[(nb * 16 + lm) * 136 + kc * 32 + g * 8];
        s[nb] = __builtin_amdgcn_mfma_f32_16x16x32_bf16(qf[kc], bk, s[nb], 0, 0, 0);
      }
    }
    const bool diag = (kt == qi);
#pragma unroll
    for (int r = 0; r < 4; r++) {
      float sv0 = s[0][r] * sc;
      float sv1 = s[1][r] * sc;
      if (diag) {
        const int rowr = wv * 16 + g * 4 + r;
        if (lm > rowr) sv0 = -1e30f;
        if (lm + 16 > rowr) sv1 = -1e30f;
      }
      float tm = fmaxf(sv0, sv1);
      tm = fmaxf(tm, __shfl_xor(tm, 1, 64));
      tm = fmaxf(tm, __shfl_xor(tm, 2, 64));
      tm = fmaxf(tm, __shfl_xor(tm, 4, 64));
      tm = fmaxf(tm, __shfl_xor(tm, 8, 64));
      const float mnew = fmaxf(m_r[r], tm);
      const float alpha = __expf(m_r[r] - mnew);
      const float p0 = __expf(sv0 - mnew);
      const float p1 = __expf(sv1 - mnew);
      float rs = p0 + p1;
      rs += __shfl_xor(rs, 1, 64);
      rs += __shfl_xor(rs, 2, 64);
      rs += __shfl_xor(rs, 4, 64);
      rs += __shfl_xor(rs, 8, 64);
      l_r[r] = l_r[r] * alpha + rs;
      m_r[r] = mnew;
#pragma unroll
      for (int nb2 = 0; nb2 < 8; nb2++) o[nb2][r] *= alpha;
      Ps[wv * 640 + (g * 4 + r) * 40 + lm] = (bf16_t)p0;
      Ps[wv * 640 + (g * 4 + r) * 40 + 16 + lm] = (bf16_t)p1;
    }
    bf16x8 pa = *(const bf16x8*)&Ps[wv * 640 + lm * 40 + g * 8];
#pragma unroll
    for (int nb2 = 0; nb2 < 8; nb2++) {
      bf16x8 bv = *(const bf16x8*)&Vts[(nb2 * 16 + lm) * 40 + g * 8];
      o[nb2] = __builtin_amdgcn_mfma_f32_16x16x32_bf16(pa, bv, o[nb2], 0, 0, 0);
    }
    __syncthreads();
  }
#pragma unroll
  for (int r = 0; r < 4; r++) {
    const float inv = 1.0f / l_r[r];
    float* dst = Out + (size_t)(b * T_ + q0 + wv * 16 + g * 4 + r) * D_;
#pragma unroll
    for (int nb2 = 0; nb2 < 8; nb2++) dst[nb2 * 16 + lm] = o[nb2][r] * inv;
  }
}

extern "C" void kernel_launch(void* const* d_in, const int* in_sizes, int n_in,
                              void* d_out, int out_size, void* d_ws,
                              size_t ws_size, hipStream_t stream) {
  const float* X = (const float*)d_in[0];
  const float* Wq = (const float*)d_in[1];
  const float* Wk = (const float*)d_in[2];
  const float* Wv = (const float*)d_in[3];
  float* Out = (float*)d_out;

  const size_t qkv_bytes = (size_t)3 * BT_ * D_ * sizeof(bf16_t);  // 6 MB
  const size_t opart_bytes = (size_t)UNITS * 32 * D_ * sizeof(float);  // 10 MB
  const size_t ml_bytes = (size_t)UNITS * 32 * sizeof(float);
  const size_t tab_bytes = (size_t)T_ * 64 * sizeof(float2);       // 1 MB

  const size_t needA = qkv_bytes + opart_bytes + 2 * ml_bytes + tab_bytes;
  const size_t needB = qkv_bytes + opart_bytes + 2 * ml_bytes;

  if (ws_size >= needA) {
    bf16_t* Qws = (bf16_t*)d_ws;
    bf16_t* Kws = Qws + (size_t)BT_ * D_;
    bf16_t* Vtws = Kws + (size_t)BT_ * D_;
    float* Opart = (float*)((char*)d_ws + qkv_bytes);
    float* Mpart = (float*)((char*)Opart + opart_bytes);
    float* Lpart = (float*)((char*)Mpart + ml_bytes);
    float2* Tab = (float2*)((char*)Lpart + ml_bytes);

    hipLaunchKernelGGL(tab_kernel, dim3(512), dim3(256), 0, stream, Tab);
    hipLaunchKernelGGL(proj_wlds_kernel, dim3(256), dim3(512), 0, stream,
                       X, Wq, Wk, Wv, Tab, Qws, Kws, Vtws);
    hipLaunchKernelGGL(attn_part_kernel, dim3(UNITS), dim3(128), 0, stream,
                       Qws, Kws, Vtws, Opart, Mpart, Lpart);
    hipLaunchKernelGGL(attn_combine_kernel, dim3(T_ / 32, B_), dim3(256), 0,
                       stream, Opart, Mpart, Lpart, Out);
  } else if (ws_size >= needB) {
    bf16_t* Qws = (bf16_t*)d_ws;
    bf16_t* Kws = Qws + (size_t)BT_ * D_;
    bf16_t* Vtws = Kws + (size_t)BT_ * D_;
    float* Opart = (float*)((char*)d_ws + qkv_bytes);
    float* Mpart = (float*)((char*)Opart + opart_bytes);
    float* Lpart = (float*)((char*)Mpart + ml_bytes);
    hipLaunchKernelGGL(proj_rope_kernel, dim3(BT_ / 64, 3), dim3(256), 0,
                       stream, X, Wq, Wk, Wv, Qws, Kws, Vtws);
    hipLaunchKernelGGL(attn_part_kernel, dim3(UNITS), dim3(128), 0, stream,
                       Qws, Kws, Vtws, Opart, Mpart, Lpart);
    hipLaunchKernelGGL(attn_combine_kernel, dim3(T_ / 32, B_), dim3(256), 0,
                       stream, Opart, Mpart, Lpart, Out);
  } else {
    bf16_t* Qws = (bf16_t*)d_ws;
    bf16_t* Kws = Qws + (size_t)BT_ * D_;
    bf16_t* Vtws = Kws + (size_t)BT_ * D_;
    hipLaunchKernelGGL(proj_rope_kernel, dim3(BT_ / 64, 3), dim3(256), 0,
                       stream, X, Wq, Wk, Wv, Qws, Kws, Vtws);
    hipLaunchKernelGGL(attn_kernel, dim3(T_ / 32, B_), dim3(128), 0, stream,
                       Qws, Kws, Vtws, Out);
  }
}

// Round 10
// 58.713 us; speedup vs baseline: 1.3136x; 1.3093x over previous
//
#include <hip/hip_runtime.h>
#include <math.h>

// CausalAttention: q/k/v = X @ W^T, RoPE(q,k), flash causal attention.
// B=4 T=2048 E=1024 D=128, f32 in/out, bf16 MFMA internally.
// Round 10: revert to R7-best config; single change: proj64 K-loop uses a
// 2-ahead counted-vmcnt pipeline (T4) — raw s_barrier (no vmcnt(0) drain),
// s_waitcnt vmcnt(4) keeps the newest stage in flight across barriers,
// sched_barrier(0) fences per rule #18. Everything else = round 7.

#define B_ 4
#define T_ 2048
#define E_ 1024
#define D_ 128
#define BT_ (B_ * T_)

#define UNITS_PER_B 160   // sum over qi of ceil(tiles(qi)/8), tiles(qi)=(qi>>1)+1
#define UNITS (UNITS_PER_B * B_)

typedef __bf16 bf16_t;
typedef __bf16 bf16x4 __attribute__((ext_vector_type(4)));
typedef __bf16 bf16x8 __attribute__((ext_vector_type(8)));
typedef float f32x4 __attribute__((ext_vector_type(4)));

#define GLD16(g, l)                                                         \
  __builtin_amdgcn_global_load_lds(                                         \
      (const __attribute__((address_space(1))) void*)(g),                   \
      (__attribute__((address_space(3))) void*)(l), 16, 0, 0)

__device__ __forceinline__ bf16x8 cvt8(float4 lo, float4 hi) {
  bf16x8 t;
  t[0] = (bf16_t)lo.x; t[1] = (bf16_t)lo.y; t[2] = (bf16_t)lo.z; t[3] = (bf16_t)lo.w;
  t[4] = (bf16_t)hi.x; t[5] = (bf16_t)hi.y; t[6] = (bf16_t)hi.z; t[7] = (bf16_t)hi.w;
  return t;
}

// ---------------------------------------------------------------------------
// Kernel 0: precast X f32->bf16, W -> Wb, RoPE table. (round 7, unchanged)
// ---------------------------------------------------------------------------
__global__ __launch_bounds__(256) void precast_kernel(
    const float* __restrict__ X, const float* __restrict__ Wq,
    const float* __restrict__ Wk, const float* __restrict__ Wv,
    bf16_t* __restrict__ Xb, bf16_t* __restrict__ Wb,
    float2* __restrict__ Tab) {
  const int XC = BT_ * E_ / 8;        // 1048576 chunks
  const int WC = 3 * D_ * E_ / 8;     // 49152 chunks
  for (int c = blockIdx.x * 256 + threadIdx.x; c < XC + WC;
       c += gridDim.x * 256) {
    const float* src;
    bf16_t* dst;
    if (c < XC) {
      src = X + (size_t)c * 8;
      dst = Xb + (size_t)c * 8;
    } else {
      const int cw = c - XC;
      const int z = cw / (D_ * E_ / 8);
      const int r = cw % (D_ * E_ / 8);
      src = ((z == 0) ? Wq : (z == 1) ? Wk : Wv) + (size_t)r * 8;
      dst = Wb + (size_t)z * D_ * E_ + (size_t)r * 8;
    }
    float4 u = *(const float4*)src;
    float4 v = *(const float4*)(src + 4);
    *(bf16x8*)dst = cvt8(u, v);
  }
  const float NLOG_ = -0.14391156514261485f;  // -ln(10000)/64
  for (int idx = blockIdx.x * 256 + threadIdx.x; idx < T_ * 64;
       idx += gridDim.x * 256) {
    const int t = idx >> 6, j = idx & 63;
    const float freq = expf(NLOG_ * (float)j);
    float sn, cs;
    sincosf((float)t * freq, &sn, &cs);
    Tab[idx] = make_float2(cs, sn);
  }
}

// ---------------------------------------------------------------------------
// Kernel 1: proj GEMM 64x64x64 + table-RoPE. grid 768, block 256.
// NEW: 2-ahead counted-vmcnt pipeline (T4). Each stage = 4 gld_lds/thread;
// vmcnt(4) leaves the newest stage in flight across both barriers.
// ---------------------------------------------------------------------------
__global__ __launch_bounds__(256) void proj64_kernel(
    const bf16_t* __restrict__ Xb, const bf16_t* __restrict__ Wb,
    const float2* __restrict__ Tab, bf16_t* __restrict__ Qws,
    bf16_t* __restrict__ Kws, bf16_t* __restrict__ Vtws) {
  const int o = blockIdx.x;
  const int ell = (o & 7) * 96 + (o >> 3);   // bijective (768 % 8 == 0)
  const int mt = ell / 6, ny = ell % 6;
  const int bt0 = mt * 64;

  const int tid = threadIdx.x;
  const int lane = tid & 63;
  const int wv = tid >> 6;                   // 0..3
  const int wr = wv >> 1, wc = wv & 1;       // wave tile 32x32
  const int g = lane >> 4, lm = lane & 15;

  __shared__ bf16_t Ab[2][64 * 64];
  __shared__ bf16_t Bb[2][64 * 64];

  const bf16_t* Wz = Wb + (size_t)ny * 64 * E_;

  f32x4 acc[2][2];
#pragma unroll
  for (int m = 0; m < 2; m++)
#pragma unroll
    for (int n = 0; n < 2; n++) acc[m][n] = 0.0f;

  auto stage = [&](int t, int bf) {
    const int k0 = t * 64;
#pragma unroll
    for (int j = 0; j < 2; j++) {
      const int cb = (wv * 2 + j) * 64;
      const int c = cb + lane;
      const int row = c >> 3;
      const int eoff = ((c & 7) * 8) ^ ((row & 7) << 3);
      GLD16(Xb + (size_t)(bt0 + row) * E_ + k0 + eoff, &Ab[bf][cb * 8]);
    }
#pragma unroll
    for (int j = 0; j < 2; j++) {
      const int cb = (wv * 2 + j) * 64;
      const int c = cb + lane;
      const int row = c >> 3;
      const int eoff = ((c & 7) * 8) ^ ((row & 7) << 3);
      GLD16(Wz + (size_t)row * E_ + k0 + eoff, &Bb[bf][cb * 8]);
    }
  };

  auto compute = [&](int bf) {
#pragma unroll
    for (int ks = 0; ks < 2; ks++) {
      bf16x8 a0, a1, b0, b1;
      {
        const int r0 = wr * 32 + lm;
        a0 = *(const bf16x8*)&Ab[bf][r0 * 64 + ((ks * 32 + g * 8) ^ ((r0 & 7) << 3))];
        const int r1 = wr * 32 + 16 + lm;
        a1 = *(const bf16x8*)&Ab[bf][r1 * 64 + ((ks * 32 + g * 8) ^ ((r1 & 7) << 3))];
        const int s0 = wc * 32 + lm;
        b0 = *(const bf16x8*)&Bb[bf][s0 * 64 + ((ks * 32 + g * 8) ^ ((s0 & 7) << 3))];
        const int s1 = wc * 32 + 16 + lm;
        b1 = *(const bf16x8*)&Bb[bf][s1 * 64 + ((ks * 32 + g * 8) ^ ((s1 & 7) << 3))];
      }
      acc[0][0] = __builtin_amdgcn_mfma_f32_16x16x32_bf16(a0, b0, acc[0][0], 0, 0, 0);
      acc[0][1] = __builtin_amdgcn_mfma_f32_16x16x32_bf16(a0, b1, acc[0][1], 0, 0, 0);
      acc[1][0] = __builtin_amdgcn_mfma_f32_16x16x32_bf16(a1, b0, acc[1][0], 0, 0, 0);
      acc[1][1] = __builtin_amdgcn_mfma_f32_16x16x32_bf16(a1, b1, acc[1][1], 0, 0, 0);
    }
  };

  // prologue: 2 tiles in flight; wait for tile0 only (vmcnt 8 -> 4)
  stage(0, 0);
  stage(1, 1);
  asm volatile("s_waitcnt vmcnt(4)" ::: "memory");
  __builtin_amdgcn_s_barrier();
  __builtin_amdgcn_sched_barrier(0);

#pragma unroll
  for (int t = 0; t < 16; t++) {
    compute(t & 1);                          // ds_reads all MFMA-consumed -> lgkm drained
    __builtin_amdgcn_sched_barrier(0);
    __builtin_amdgcn_s_barrier();            // [A] all waves done reading buf[t&1]
    __builtin_amdgcn_sched_barrier(0);
    if (t + 2 < 16) {
      stage(t + 2, t & 1);                   // refill freed buffer (4 new gld_lds)
      asm volatile("s_waitcnt vmcnt(4)" ::: "memory");  // stage(t+1) landed
    } else {
      asm volatile("s_waitcnt vmcnt(0)" ::: "memory");  // drain tail
    }
    __builtin_amdgcn_sched_barrier(0);
    __builtin_amdgcn_s_barrier();            // [B] tile t+1 visible to all waves
    __builtin_amdgcn_sched_barrier(0);
  }

  // Epilogue: frag (mf,nf): row = bt0+wr*32+mf*16+g*4+r,
  // col = ny*64+wc*32+nf*16+lm. z = col>>7, d = col&127. Table RoPE.
  const int b = bt0 >> 11;
#pragma unroll
  for (int nf = 0; nf < 2; nf++) {
    const int col = ny * 64 + wc * 32 + nf * 16 + lm;
    const int z = col >> 7;
    const int d = col & 127;
#pragma unroll
    for (int mf = 0; mf < 2; mf++) {
      const int row0 = bt0 + wr * 32 + mf * 16 + g * 4;
      if (z < 2) {
        bf16_t* dst = (z == 0) ? Qws : Kws;
#pragma unroll
        for (int r = 0; r < 4; r++) {
          const int bt = row0 + r;
          const int tt = bt & (T_ - 1);
          float val = acc[mf][nf][r];
          float prt = __shfl_xor(val, 1, 64);
          const float2 cs = Tab[(size_t)tt * 64 + (d >> 1)];
          const float outv =
              (d & 1) ? (prt * cs.y + val * cs.x) : (val * cs.x - prt * cs.y);
          dst[(size_t)bt * D_ + d] = (bf16_t)outv;
        }
      } else {
        bf16x4 pv;
#pragma unroll
        for (int r = 0; r < 4; r++) pv[r] = (bf16_t)acc[mf][nf][r];
        const int tt0 = row0 & (T_ - 1);
        *(bf16x4*)&Vtws[((size_t)(b * D_ + d)) * T_ + tt0] = pv;
      }
    }
  }
}

// ---------------------------------------------------------------------------
// Kernel 2a: KV-split causal flash attention partials (R7, T14 async-stage).
// ---------------------------------------------------------------------------
__global__ __launch_bounds__(128) void attn_part_kernel(
    const bf16_t* __restrict__ Qws, const bf16_t* __restrict__ Kws,
    const bf16_t* __restrict__ Vtws, float* __restrict__ Opart,
    float* __restrict__ Mpart, float* __restrict__ Lpart) {
  const int idx = blockIdx.x;
  const int b = idx / UNITS_PER_B;
  const int rem = idx % UNITS_PER_B;
  int qi, ci;
  if (rem < 16) { qi = rem; ci = 0; }
  else if (rem < 48) { int r2 = rem - 16; qi = 16 + (r2 >> 1); ci = r2 & 1; }
  else if (rem < 96) { int r2 = rem - 48; qi = 32 + r2 / 3; ci = r2 % 3; }
  else { int r2 = rem - 96; qi = 48 + (r2 >> 2); ci = r2 & 3; }
  const int slot = idx;

  const int q0 = qi * 32;
  const int tiles = (qi >> 1) + 1;
  const int t0 = ci * 8;
  const int t1 = min(t0 + 8, tiles);

  const int tid = threadIdx.x;
  const int lane = tid & 63;
  const int wv = tid >> 6;
  const int g = lane >> 4;
  const int lm = lane & 15;

  __shared__ bf16_t Ks[64 * 136];
  __shared__ bf16_t Vts[128 * 72];
  __shared__ bf16_t Ps[2 * 16 * 72];

  bf16x8 qf[4];
  {
    const bf16_t* qb = Qws + (size_t)(b * T_ + q0 + wv * 16 + lm) * D_;
#pragma unroll
    for (int kc = 0; kc < 4; kc++) qf[kc] = *(const bf16x8*)(qb + kc * 32 + g * 8);
  }

  f32x4 o[8];
#pragma unroll
  for (int i = 0; i < 8; i++) o[i] = 0.0f;
  float m_r[4], l_r[4];
#pragma unroll
  for (int r = 0; r < 4; r++) { m_r[r] = -1e30f; l_r[r] = 0.0f; }
  const float sc = 0.08838834764831845f;

  bf16x8 kreg[8], vreg[8];
  auto load_tiles = [&](int it) {
    const int k0 = it * 64;
#pragma unroll
    for (int i = 0; i < 8; i++) {
      const int c = tid + i * 128;
      kreg[i] = *(const bf16x8*)(Kws + (size_t)(b * T_ + k0 + (c >> 4)) * D_ +
                                 (c & 15) * 8);
    }
#pragma unroll
    for (int i = 0; i < 8; i++) {
      const int c = tid + i * 128;
      vreg[i] = *(const bf16x8*)(Vtws + (size_t)(b * D_ + (c >> 3)) * T_ + k0 +
                                 (c & 7) * 8);
    }
  };
  auto write_lds = [&]() {
#pragma unroll
    for (int i = 0; i < 8; i++) {
      const int c = tid + i * 128;
      *(bf16x8*)&Ks[(c >> 4) * 136 + (c & 15) * 8] = kreg[i];
    }
#pragma unroll
    for (int i = 0; i < 8; i++) {
      const int c = tid + i * 128;
      *(bf16x8*)&Vts[(c >> 3) * 72 + (c & 7) * 8] = vreg[i];
    }
  };

  load_tiles(t0);
  for (int it = t0; it < t1; it++) {
    write_lds();
    __syncthreads();
    if (it + 1 < t1) load_tiles(it + 1);   // overlaps with compute below

    const int k0 = it * 64;
    f32x4 s[4];
#pragma unroll
    for (int nb = 0; nb < 4; nb++) s[nb] = 0.0f;
#pragma unroll
    for (int nb = 0; nb < 4; nb++) {
#pragma unroll
      for (int kc = 0; kc < 4; kc++) {
        bf16x8 bk = *(const bf16x8*)&Ks[(nb * 16 + lm) * 136 + kc * 32 + g * 8];
        s[nb] = __builtin_amdgcn_mfma_f32_16x16x32_bf16(qf[kc], bk, s[nb], 0, 0, 0);
      }
    }

    const bool diag = (it == tiles - 1);
#pragma unroll
    for (int r = 0; r < 4; r++) {
      const int qrow = q0 + wv * 16 + g * 4 + r;
      float sv[4];
#pragma unroll
      for (int nb = 0; nb < 4; nb++) {
        sv[nb] = s[nb][r] * sc;
        if (diag && (k0 + nb * 16 + lm > qrow)) sv[nb] = -1e30f;
      }
      float tm = fmaxf(fmaxf(sv[0], sv[1]), fmaxf(sv[2], sv[3]));
      tm = fmaxf(tm, __shfl_xor(tm, 1, 64));
      tm = fmaxf(tm, __shfl_xor(tm, 2, 64));
      tm = fmaxf(tm, __shfl_xor(tm, 4, 64));
      tm = fmaxf(tm, __shfl_xor(tm, 8, 64));
      const float mnew = fmaxf(m_r[r], tm);
      const float alpha = __expf(m_r[r] - mnew);
      float p[4], rs = 0.0f;
#pragma unroll
      for (int nb = 0; nb < 4; nb++) { p[nb] = __expf(sv[nb] - mnew); rs += p[nb]; }
      rs += __shfl_xor(rs, 1, 64);
      rs += __shfl_xor(rs, 2, 64);
      rs += __shfl_xor(rs, 4, 64);
      rs += __shfl_xor(rs, 8, 64);
      l_r[r] = l_r[r] * alpha + rs;
      m_r[r] = mnew;
#pragma unroll
      for (int nb2 = 0; nb2 < 8; nb2++) o[nb2][r] *= alpha;
#pragma unroll
      for (int nb = 0; nb < 4; nb++)
        Ps[wv * 1152 + (g * 4 + r) * 72 + nb * 16 + lm] = (bf16_t)p[nb];
    }

    bf16x8 pa0 = *(const bf16x8*)&Ps[wv * 1152 + lm * 72 + g * 8];
    bf16x8 pa1 = *(const bf16x8*)&Ps[wv * 1152 + lm * 72 + 32 + g * 8];
#pragma unroll
    for (int nb2 = 0; nb2 < 8; nb2++) {
      bf16x8 bv0 = *(const bf16x8*)&Vts[(nb2 * 16 + lm) * 72 + g * 8];
      o[nb2] = __builtin_amdgcn_mfma_f32_16x16x32_bf16(pa0, bv0, o[nb2], 0, 0, 0);
      bf16x8 bv1 = *(const bf16x8*)&Vts[(nb2 * 16 + lm) * 72 + 32 + g * 8];
      o[nb2] = __builtin_amdgcn_mfma_f32_16x16x32_bf16(pa1, bv1, o[nb2], 0, 0, 0);
    }
    __syncthreads();
  }

#pragma unroll
  for (int r = 0; r < 4; r++) {
    const int row = wv * 16 + g * 4 + r;
    if (lm == 0) {
      Mpart[slot * 32 + row] = m_r[r];
      Lpart[slot * 32 + row] = l_r[r];
    }
    float* dst = Opart + ((size_t)slot * 32 + row) * D_;
#pragma unroll
    for (int nb2 = 0; nb2 < 8; nb2++) dst[nb2 * 16 + lm] = o[nb2][r];
  }
}

// ---------------------------------------------------------------------------
// Kernel 2b: combine partials. grid (T/32, B), block 256. (unchanged)
// ---------------------------------------------------------------------------
__global__ __launch_bounds__(256) void attn_combine_kernel(
    const float* __restrict__ Opart, const float* __restrict__ Mpart,
    const float* __restrict__ Lpart, float* __restrict__ Out) {
  const int qi = blockIdx.x;
  const int b = blockIdx.y;
  const int gg = qi >> 4;
  const int nc = gg + 1;
  const int base = b * UNITS_PER_B + ((gg * (gg + 1)) / 2) * 16 + (qi & 15) * nc;
  const int t = threadIdx.x;
  const int row = t >> 3;
  const int d0 = (t & 7) * 16;

  float mv[4];
  float mmax = -1e30f;
  for (int ci = 0; ci < nc; ci++) {
    mv[ci] = Mpart[(base + ci) * 32 + row];
    mmax = fmaxf(mmax, mv[ci]);
  }
  f32x4 acc[4];
#pragma unroll
  for (int j = 0; j < 4; j++) acc[j] = 0.0f;
  float l = 0.0f;
  for (int ci = 0; ci < nc; ci++) {
    const float w = __expf(mv[ci] - mmax);
    l += w * Lpart[(base + ci) * 32 + row];
    const float* op = Opart + ((size_t)(base + ci) * 32 + row) * D_ + d0;
#pragma unroll
    for (int j = 0; j < 4; j++) {
      float4 v = *(const float4*)(op + j * 4);
      acc[j][0] += w * v.x; acc[j][1] += w * v.y;
      acc[j][2] += w * v.z; acc[j][3] += w * v.w;
    }
  }
  const float inv = 1.0f / l;
  float* dst = Out + ((size_t)(b * T_ + qi * 32 + row)) * D_ + d0;
#pragma unroll
  for (int j = 0; j < 4; j++) {
    float4 v;
    v.x = acc[j][0] * inv; v.y = acc[j][1] * inv;
    v.z = acc[j][2] * inv; v.w = acc[j][3] * inv;
    *(float4*)(dst + j * 4) = v;
  }
}

// ---------------------------------------------------------------------------
// Fallback proj (round-1): direct f32 inputs, M64 tile. grid (BT/64,3), 256.
// ---------------------------------------------------------------------------
__global__ __launch_bounds__(256) void proj_rope_kernel(
    const float* __restrict__ X, const float* __restrict__ Wq,
    const float* __restrict__ Wk, const float* __restrict__ Wv,
    bf16_t* __restrict__ Qws, bf16_t* __restrict__ Kws,
    bf16_t* __restrict__ Vtws) {
  const int z = blockIdx.y;
  const float* __restrict__ W = (z == 0) ? Wq : (z == 1) ? Wk : Wv;
  const int bt0 = blockIdx.x * 64;
  const int tid = threadIdx.x;
  const int lane = tid & 63;
  const int wv = tid >> 6;
  const int g = lane >> 4;
  const int lm = lane & 15;

  __shared__ bf16_t Xs[64 * 40];
  __shared__ bf16_t Ws[128 * 40];

  f32x4 acc[8];
#pragma unroll
  for (int i = 0; i < 8; i++) acc[i] = 0.0f;

  for (int kk = 0; kk < E_ / 32; kk++) {
    {
      const int row = tid >> 2, c0 = (tid & 3) * 8;
      const float* src = X + (size_t)(bt0 + row) * E_ + kk * 32 + c0;
      float4 u = *(const float4*)src;
      float4 v = *(const float4*)(src + 4);
      *(bf16x8*)&Xs[row * 40 + c0] = cvt8(u, v);
    }
#pragma unroll
    for (int h = 0; h < 2; h++) {
      const int cc = tid * 2 + h;
      const int row = cc >> 2, c0 = (cc & 3) * 8;
      const float* src = W + (size_t)row * E_ + kk * 32 + c0;
      float4 u = *(const float4*)src;
      float4 v = *(const float4*)(src + 4);
      *(bf16x8*)&Ws[row * 40 + c0] = cvt8(u, v);
    }
    __syncthreads();
    bf16x8 a = *(const bf16x8*)&Xs[(wv * 16 + lm) * 40 + g * 8];
#pragma unroll
    for (int nb = 0; nb < 8; nb++) {
      bf16x8 bb = *(const bf16x8*)&Ws[(nb * 16 + lm) * 40 + g * 8];
      acc[nb] = __builtin_amdgcn_mfma_f32_16x16x32_bf16(a, bb, acc[nb], 0, 0, 0);
    }
    __syncthreads();
  }
  const float NLOG_ = -0.14391156514261485f;
#pragma unroll
  for (int nb = 0; nb < 8; nb++) {
    const int col = nb * 16 + lm;
    const float freq = expf(NLOG_ * (float)(col >> 1));
#pragma unroll
    for (int r = 0; r < 4; r++) {
      const int bt = bt0 + wv * 16 + g * 4 + r;
      float val = acc[nb][r];
      float prt = __shfl_xor(val, 1, 64);
      if (z < 2) {
        const int t = bt & (T_ - 1);
        const float ang = (float)t * freq;
        float sn, cs;
        sincosf(ang, &sn, &cs);
        const float outv = (col & 1) ? (prt * sn + val * cs) : (val * cs - prt * sn);
        bf16_t* dst = (z == 0) ? Qws : Kws;
        dst[(size_t)bt * D_ + col] = (bf16_t)outv;
      } else {
        const int b = bt >> 11, t = bt & (T_ - 1);
        Vtws[((size_t)(b * D_ + col)) * T_ + t] = (bf16_t)val;
      }
    }
  }
}

// ---------------------------------------------------------------------------
// Fallback: single-pass flash attention (round-1 kernel)
// ---------------------------------------------------------------------------
__global__ __launch_bounds__(128) void attn_kernel(
    const bf16_t* __restrict__ Qws, const bf16_t* __restrict__ Kws,
    const bf16_t* __restrict__ Vtws, float* __restrict__ Out) {
  const int b = blockIdx.y;
  const int qi = blockIdx.x;
  const int q0 = qi * 32;
  const int tid = threadIdx.x;
  const int lane = tid & 63;
  const int wv = tid >> 6;
  const int g = lane >> 4;
  const int lm = lane & 15;

  __shared__ bf16_t Ks[32 * 136];
  __shared__ bf16_t Vts[128 * 40];
  __shared__ bf16_t Ps[2 * 16 * 40];

  bf16x8 qf[4];
  {
    const bf16_t* qb = Qws + (size_t)(b * T_ + q0 + wv * 16 + lm) * D_;
#pragma unroll
    for (int kk = 0; kk < 4; kk++) qf[kk] = *(const bf16x8*)(qb + kk * 32 + g * 8);
  }
  f32x4 o[8];
#pragma unroll
  for (int i = 0; i < 8; i++) o[i] = 0.0f;
  float m_r[4], l_r[4];
#pragma unroll
  for (int r = 0; r < 4; r++) { m_r[r] = -1e30f; l_r[r] = 0.0f; }
  const float sc = 0.08838834764831845f;

  for (int kt = 0; kt <= qi; kt++) {
    const int kv0 = kt * 32;
#pragma unroll
    for (int i = 0; i < 4; i++) {
      const int c = tid + i * 128;
      const int row = c >> 4, part = c & 15;
      bf16x8 v = *(const bf16x8*)(Kws + (size_t)(b * T_ + kv0 + row) * D_ + part * 8);
      *(bf16x8*)&Ks[row * 136 + part * 8] = v;
    }
#pragma unroll
    for (int i = 0; i < 4; i++) {
      const int c = tid + i * 128;
      const int d = c >> 2, part = c & 3;
      bf16x8 v = *(const bf16x8*)(Vtws + (size_t)(b * D_ + d) * T_ + kv0 + part * 8);
      *(bf16x8*)&Vts[d * 40 + part * 8] = v;
    }
    __syncthreads();
    f32x4 s[2];
    s[0] = 0.0f; s[1] = 0.0f;
#pragma unroll
    for (int nb = 0; nb < 2; nb++) {
#pragma unroll
      for (int kc = 0; kc < 4; kc++) {
        bf16x8 bk = *(const bf16x8*)&Ks[(nb * 16 + lm) * 136 + kc * 32 + g * 8];
        s[nb] = __builtin_amdgcn_mfma_f32_16x16x32_bf16(qf[kc], bk, s[nb], 0, 0, 0);
      }
    }
    const bool diag = (kt == qi);
#pragma unroll
    for (int r = 0; r < 4; r++) {
      float sv0 = s[0][r] * sc;
      float sv1 = s[1][r] * sc;
      if (diag) {
        const int rowr = wv * 16 + g * 4 + r;
        if (lm > rowr) sv0 = -1e30f;
        if (lm + 16 > rowr) sv1 = -1e30f;
      }
      float tm = fmaxf(sv0, sv1);
      tm = fmaxf(tm, __shfl_xor(tm, 1, 64));
      tm = fmaxf(tm, __shfl_xor(tm, 2, 64));
      tm = fmaxf(tm, __shfl_xor(tm, 4, 64));
      tm = fmaxf(tm, __shfl_xor(tm, 8, 64));
      const float mnew = fmaxf(m_r[r], tm);
      const float alpha = __expf(m_r[r] - mnew);
      const float p0 = __expf(sv0 - mnew);
      const float p1 = __expf(sv1 - mnew);
      float rs = p0 + p1;
      rs += __shfl_xor(rs, 1, 64);
      rs += __shfl_xor(rs, 2, 64);
      rs += __shfl_xor(rs, 4, 64);
      rs += __shfl_xor(rs, 8, 64);
      l_r[r] = l_r[r] * alpha + rs;
      m_r[r] = mnew;
#pragma unroll
      for (int nb2 = 0; nb2 < 8; nb2++) o[nb2][r] *= alpha;
      Ps[wv * 640 + (g * 4 + r) * 40 + lm] = (bf16_t)p0;
      Ps[wv * 640 + (g * 4 + r) * 40 + 16 + lm] = (bf16_t)p1;
    }
    bf16x8 pa = *(const bf16x8*)&Ps[wv * 640 + lm * 40 + g * 8];
#pragma unroll
    for (int nb2 = 0; nb2 < 8; nb2++) {
      bf16x8 bv = *(const bf16x8*)&Vts[(nb2 * 16 + lm) * 40 + g * 8];
      o[nb2] = __builtin_amdgcn_mfma_f32_16x16x32_bf16(pa, bv, o[nb2], 0, 0, 0);
    }
    __syncthreads();
  }
#pragma unroll
  for (int r = 0; r < 4; r++) {
    const float inv = 1.0f / l_r[r];
    float* dst = Out + (size_t)(b * T_ + q0 + wv * 16 + g * 4 + r) * D_;
#pragma unroll
    for (int nb2 = 0; nb2 < 8; nb2++) dst[nb2 * 16 + lm] = o[nb2][r] * inv;
  }
}

extern "C" void kernel_launch(void* const* d_in, const int* in_sizes, int n_in,
                              void* d_out, int out_size, void* d_ws,
                              size_t ws_size, hipStream_t stream) {
  const float* X = (const float*)d_in[0];
  const float* Wq = (const float*)d_in[1];
  const float* Wk = (const float*)d_in[2];
  const float* Wv = (const float*)d_in[3];
  float* Out = (float*)d_out;

  const size_t xb_bytes = (size_t)BT_ * E_ * sizeof(bf16_t);       // 16 MB
  const size_t wb_bytes = (size_t)3 * D_ * E_ * sizeof(bf16_t);    // 0.75 MB
  const size_t qkv_bytes = (size_t)3 * BT_ * D_ * sizeof(bf16_t);  // 6 MB
  const size_t opart_bytes = (size_t)UNITS * 32 * D_ * sizeof(float);  // 10 MB
  const size_t ml_bytes = (size_t)UNITS * 32 * sizeof(float);
  const size_t tab_bytes = (size_t)T_ * 64 * sizeof(float2);       // 1 MB

  const size_t needA =
      xb_bytes + wb_bytes + qkv_bytes + opart_bytes + 2 * ml_bytes + tab_bytes;
  const size_t needB = qkv_bytes + opart_bytes + 2 * ml_bytes;

  if (ws_size >= needA) {
    bf16_t* Xb = (bf16_t*)d_ws;
    bf16_t* Wb = Xb + (size_t)BT_ * E_;
    bf16_t* Qws = Wb + (size_t)3 * D_ * E_;
    bf16_t* Kws = Qws + (size_t)BT_ * D_;
    bf16_t* Vtws = Kws + (size_t)BT_ * D_;
    float* Opart = (float*)((char*)d_ws + xb_bytes + wb_bytes + qkv_bytes);
    float* Mpart = (float*)((char*)Opart + opart_bytes);
    float* Lpart = (float*)((char*)Mpart + ml_bytes);
    float2* Tab = (float2*)((char*)Lpart + ml_bytes);

    hipLaunchKernelGGL(precast_kernel, dim3(2048), dim3(256), 0, stream,
                       X, Wq, Wk, Wv, Xb, Wb, Tab);
    hipLaunchKernelGGL(proj64_kernel, dim3(768), dim3(256), 0, stream,
                       Xb, Wb, Tab, Qws, Kws, Vtws);
    hipLaunchKernelGGL(attn_part_kernel, dim3(UNITS), dim3(128), 0, stream,
                       Qws, Kws, Vtws, Opart, Mpart, Lpart);
    hipLaunchKernelGGL(attn_combine_kernel, dim3(T_ / 32, B_), dim3(256), 0,
                       stream, Opart, Mpart, Lpart, Out);
  } else if (ws_size >= needB) {
    bf16_t* Qws = (bf16_t*)d_ws;
    bf16_t* Kws = Qws + (size_t)BT_ * D_;
    bf16_t* Vtws = Kws + (size_t)BT_ * D_;
    float* Opart = (float*)((char*)d_ws + qkv_bytes);
    float* Mpart = (float*)((char*)Opart + opart_bytes);
    float* Lpart = (float*)((char*)Mpart + ml_bytes);
    hipLaunchKernelGGL(proj_rope_kernel, dim3(BT_ / 64, 3), dim3(256), 0,
                       stream, X, Wq, Wk, Wv, Qws, Kws, Vtws);
    hipLaunchKernelGGL(attn_part_kernel, dim3(UNITS), dim3(128), 0, stream,
                       Qws, Kws, Vtws, Opart, Mpart, Lpart);
    hipLaunchKernelGGL(attn_combine_kernel, dim3(T_ / 32, B_), dim3(256), 0,
                       stream, Opart, Mpart, Lpart, Out);
  } else {
    bf16_t* Qws = (bf16_t*)d_ws;
    bf16_t* Kws = Qws + (size_t)BT_ * D_;
    bf16_t* Vtws = Kws + (size_t)BT_ * D_;
    hipLaunchKernelGGL(proj_rope_kernel, dim3(BT_ / 64, 3), dim3(256), 0,
                       stream, X, Wq, Wk, Wv, Qws, Kws, Vtws);
    hipLaunchKernelGGL(attn_kernel, dim3(T_ / 32, B_), dim3(128), 0, stream,
                       Qws, Kws, Vtws, Out);
  }
}

// Round 11
// 58.379 us; speedup vs baseline: 1.3211x; 1.0057x over previous
//
#include <hip/hip_runtime.h>
#include <math.h>

// CausalAttention: q/k/v = X @ W^T, RoPE(q,k), flash causal attention.
// B=4 T=2048 E=1024 D=128, f32 in/out, bf16 MFMA internally.
// Round 11: fold X precast INTO proj64 — X staged as raw f32 via
// global_load_lds (pre-swizzled source, chunk^=(row&15), read 2-way = free),
// converted f32->bf16 in-register after ds_read_b128. Kills the 48MB
// precast round-trip. W+Tab keep a tiny precast. Counted-vmcnt (R10) kept,
// now vmcnt(6). Attn path unchanged.

#define B_ 4
#define T_ 2048
#define E_ 1024
#define D_ 128
#define BT_ (B_ * T_)

#define UNITS_PER_B 160   // sum over qi of ceil(tiles(qi)/8), tiles(qi)=(qi>>1)+1
#define UNITS (UNITS_PER_B * B_)

typedef __bf16 bf16_t;
typedef __bf16 bf16x4 __attribute__((ext_vector_type(4)));
typedef __bf16 bf16x8 __attribute__((ext_vector_type(8)));
typedef float f32x4 __attribute__((ext_vector_type(4)));

#define GLD16(g, l)                                                         \
  __builtin_amdgcn_global_load_lds(                                         \
      (const __attribute__((address_space(1))) void*)(g),                   \
      (__attribute__((address_space(3))) void*)(l), 16, 0, 0)

__device__ __forceinline__ bf16x8 cvt8(float4 lo, float4 hi) {
  bf16x8 t;
  t[0] = (bf16_t)lo.x; t[1] = (bf16_t)lo.y; t[2] = (bf16_t)lo.z; t[3] = (bf16_t)lo.w;
  t[4] = (bf16_t)hi.x; t[5] = (bf16_t)hi.y; t[6] = (bf16_t)hi.z; t[7] = (bf16_t)hi.w;
  return t;
}
__device__ __forceinline__ bf16x8 cvt8v(f32x4 lo, f32x4 hi) {
  bf16x8 t;
  t[0] = (bf16_t)lo[0]; t[1] = (bf16_t)lo[1]; t[2] = (bf16_t)lo[2]; t[3] = (bf16_t)lo[3];
  t[4] = (bf16_t)hi[0]; t[5] = (bf16_t)hi[1]; t[6] = (bf16_t)hi[2]; t[7] = (bf16_t)hi[3];
  return t;
}

// ---------------------------------------------------------------------------
// Kernel 0: tiny precast — W (3x 128x1024 f32) -> Wb bf16, RoPE table.
// grid 256, block 256.
// ---------------------------------------------------------------------------
__global__ __launch_bounds__(256) void wtab_kernel(
    const float* __restrict__ Wq, const float* __restrict__ Wk,
    const float* __restrict__ Wv, bf16_t* __restrict__ Wb,
    float2* __restrict__ Tab) {
  const int gidx = blockIdx.x * 256 + threadIdx.x;  // 0..65535
  if (gidx < 3 * D_ * E_ / 8) {                     // 49152 W chunks
    const int z = gidx / 16384;
    const int r = gidx % 16384;
    const float* src = ((z == 0) ? Wq : (z == 1) ? Wk : Wv) + (size_t)r * 8;
    float4 u = *(const float4*)src;
    float4 v = *(const float4*)(src + 4);
    *(bf16x8*)(Wb + (size_t)z * D_ * E_ + (size_t)r * 8) = cvt8(u, v);
  }
  const float NLOG_ = -0.14391156514261485f;  // -ln(10000)/64
  for (int idx = gidx; idx < T_ * 64; idx += 65536) {
    const int t = idx >> 6, j = idx & 63;
    const float freq = expf(NLOG_ * (float)j);
    float sn, cs;
    sincosf((float)t * freq, &sn, &cs);
    Tab[idx] = make_float2(cs, sn);
  }
}

// ---------------------------------------------------------------------------
// Kernel 1: proj GEMM 64x64x64 + table-RoPE. grid 768, block 256.
// X staged as f32 via gld_lds (swizzled source: 16B-chunk ^= row&15);
// W staged bf16 (as R10). 2-ahead counted-vmcnt(6) pipeline.
// ---------------------------------------------------------------------------
__global__ __launch_bounds__(256) void proj64_kernel(
    const float* __restrict__ X, const bf16_t* __restrict__ Wb,
    const float2* __restrict__ Tab, bf16_t* __restrict__ Qws,
    bf16_t* __restrict__ Kws, bf16_t* __restrict__ Vtws) {
  const int o = blockIdx.x;
  const int ell = (o & 7) * 96 + (o >> 3);   // bijective (768 % 8 == 0)
  const int mt = ell / 6, ny = ell % 6;
  const int bt0 = mt * 64;

  const int tid = threadIdx.x;
  const int lane = tid & 63;
  const int wv = tid >> 6;                   // 0..3
  const int wr = wv >> 1, wc = wv & 1;       // wave tile 32x32
  const int g = lane >> 4, lm = lane & 15;

  __shared__ float Axf[2][64 * 64];          // 16 KB each, f32, swizzled
  __shared__ bf16_t Bb[2][64 * 64];          // 8 KB each

  const bf16_t* Wz = Wb + (size_t)ny * 64 * E_;

  f32x4 acc[2][2];
#pragma unroll
  for (int m = 0; m < 2; m++)
#pragma unroll
    for (int n = 0; n < 2; n++) acc[m][n] = 0.0f;

  // stage = 6 gld_lds/thread: 4 X-f32 chunks + 2 W-bf16 chunks
  auto stage = [&](int t, int bf) {
    const int k0 = t * 64;
#pragma unroll
    for (int j = 0; j < 4; j++) {
      const int cb = (wv * 4 + j) * 64;      // wave-uniform chunk base (0..1023)
      const int L = cb + lane;               // this lane's 16B chunk
      const int row = L >> 4;                // 0..63
      const int pch = L & 15;                // physical chunk in row
      const int c = pch ^ (row & 15);        // logical chunk (inverse swz src)
      GLD16(X + (size_t)(bt0 + row) * E_ + k0 + c * 4, &Axf[bf][cb * 4]);
    }
#pragma unroll
    for (int j = 0; j < 2; j++) {
      const int cb = (wv * 2 + j) * 64;
      const int c = cb + lane;
      const int row = c >> 3;
      const int eoff = ((c & 7) * 8) ^ ((row & 7) << 3);
      GLD16(Wz + (size_t)row * E_ + k0 + eoff, &Bb[bf][cb * 8]);
    }
  };

  auto compute = [&](int bf) {
#pragma unroll
    for (int ks = 0; ks < 2; ks++) {
      const int cc = ks * 8 + g * 2;         // logical 16B-chunk pair base
      bf16x8 a0, a1, b0, b1;
      {
        const int r0 = wr * 32 + lm;
        f32x4 lo0 = *(const f32x4*)&Axf[bf][r0 * 64 + (cc ^ (r0 & 15)) * 4];
        f32x4 hi0 = *(const f32x4*)&Axf[bf][r0 * 64 + ((cc + 1) ^ (r0 & 15)) * 4];
        a0 = cvt8v(lo0, hi0);
        const int r1 = wr * 32 + 16 + lm;
        f32x4 lo1 = *(const f32x4*)&Axf[bf][r1 * 64 + (cc ^ (r1 & 15)) * 4];
        f32x4 hi1 = *(const f32x4*)&Axf[bf][r1 * 64 + ((cc + 1) ^ (r1 & 15)) * 4];
        a1 = cvt8v(lo1, hi1);
        const int s0 = wc * 32 + lm;
        b0 = *(const bf16x8*)&Bb[bf][s0 * 64 + ((ks * 32 + g * 8) ^ ((s0 & 7) << 3))];
        const int s1 = wc * 32 + 16 + lm;
        b1 = *(const bf16x8*)&Bb[bf][s1 * 64 + ((ks * 32 + g * 8) ^ ((s1 & 7) << 3))];
      }
      acc[0][0] = __builtin_amdgcn_mfma_f32_16x16x32_bf16(a0, b0, acc[0][0], 0, 0, 0);
      acc[0][1] = __builtin_amdgcn_mfma_f32_16x16x32_bf16(a0, b1, acc[0][1], 0, 0, 0);
      acc[1][0] = __builtin_amdgcn_mfma_f32_16x16x32_bf16(a1, b0, acc[1][0], 0, 0, 0);
      acc[1][1] = __builtin_amdgcn_mfma_f32_16x16x32_bf16(a1, b1, acc[1][1], 0, 0, 0);
    }
  };

  // prologue: 2 tiles in flight; wait for tile0 only (12 -> 6 outstanding)
  stage(0, 0);
  stage(1, 1);
  asm volatile("s_waitcnt vmcnt(6)" ::: "memory");
  __builtin_amdgcn_s_barrier();
  __builtin_amdgcn_sched_barrier(0);

#pragma unroll
  for (int t = 0; t < 16; t++) {
    compute(t & 1);                          // ds_reads all MFMA-consumed
    __builtin_amdgcn_sched_barrier(0);
    __builtin_amdgcn_s_barrier();            // [A] all waves done with buf[t&1]
    __builtin_amdgcn_sched_barrier(0);
    if (t + 2 < 16) {
      stage(t + 2, t & 1);                   // refill freed buffer (6 gld_lds)
      asm volatile("s_waitcnt vmcnt(6)" ::: "memory");  // stage(t+1) landed
    } else {
      asm volatile("s_waitcnt vmcnt(0)" ::: "memory");  // drain tail
    }
    __builtin_amdgcn_sched_barrier(0);
    __builtin_amdgcn_s_barrier();            // [B] tile t+1 visible
    __builtin_amdgcn_sched_barrier(0);
  }

  // Epilogue: frag (mf,nf): row = bt0+wr*32+mf*16+g*4+r,
  // col = ny*64+wc*32+nf*16+lm. z = col>>7, d = col&127. Table RoPE.
  const int b = bt0 >> 11;
#pragma unroll
  for (int nf = 0; nf < 2; nf++) {
    const int col = ny * 64 + wc * 32 + nf * 16 + lm;
    const int z = col >> 7;
    const int d = col & 127;
#pragma unroll
    for (int mf = 0; mf < 2; mf++) {
      const int row0 = bt0 + wr * 32 + mf * 16 + g * 4;
      if (z < 2) {
        bf16_t* dst = (z == 0) ? Qws : Kws;
#pragma unroll
        for (int r = 0; r < 4; r++) {
          const int bt = row0 + r;
          const int tt = bt & (T_ - 1);
          float val = acc[mf][nf][r];
          float prt = __shfl_xor(val, 1, 64);
          const float2 cs = Tab[(size_t)tt * 64 + (d >> 1)];
          const float outv =
              (d & 1) ? (prt * cs.y + val * cs.x) : (val * cs.x - prt * cs.y);
          dst[(size_t)bt * D_ + d] = (bf16_t)outv;
        }
      } else {
        bf16x4 pv;
#pragma unroll
        for (int r = 0; r < 4; r++) pv[r] = (bf16_t)acc[mf][nf][r];
        const int tt0 = row0 & (T_ - 1);
        *(bf16x4*)&Vtws[((size_t)(b * D_ + d)) * T_ + tt0] = pv;
      }
    }
  }
}

// ---------------------------------------------------------------------------
// Kernel 2a: KV-split causal flash attention partials (R7, T14 async-stage).
// ---------------------------------------------------------------------------
__global__ __launch_bounds__(128) void attn_part_kernel(
    const bf16_t* __restrict__ Qws, const bf16_t* __restrict__ Kws,
    const bf16_t* __restrict__ Vtws, float* __restrict__ Opart,
    float* __restrict__ Mpart, float* __restrict__ Lpart) {
  const int idx = blockIdx.x;
  const int b = idx / UNITS_PER_B;
  const int rem = idx % UNITS_PER_B;
  int qi, ci;
  if (rem < 16) { qi = rem; ci = 0; }
  else if (rem < 48) { int r2 = rem - 16; qi = 16 + (r2 >> 1); ci = r2 & 1; }
  else if (rem < 96) { int r2 = rem - 48; qi = 32 + r2 / 3; ci = r2 % 3; }
  else { int r2 = rem - 96; qi = 48 + (r2 >> 2); ci = r2 & 3; }
  const int slot = idx;

  const int q0 = qi * 32;
  const int tiles = (qi >> 1) + 1;
  const int t0 = ci * 8;
  const int t1 = min(t0 + 8, tiles);

  const int tid = threadIdx.x;
  const int lane = tid & 63;
  const int wv = tid >> 6;
  const int g = lane >> 4;
  const int lm = lane & 15;

  __shared__ bf16_t Ks[64 * 136];
  __shared__ bf16_t Vts[128 * 72];
  __shared__ bf16_t Ps[2 * 16 * 72];

  bf16x8 qf[4];
  {
    const bf16_t* qb = Qws + (size_t)(b * T_ + q0 + wv * 16 + lm) * D_;
#pragma unroll
    for (int kc = 0; kc < 4; kc++) qf[kc] = *(const bf16x8*)(qb + kc * 32 + g * 8);
  }

  f32x4 o[8];
#pragma unroll
  for (int i = 0; i < 8; i++) o[i] = 0.0f;
  float m_r[4], l_r[4];
#pragma unroll
  for (int r = 0; r < 4; r++) { m_r[r] = -1e30f; l_r[r] = 0.0f; }
  const float sc = 0.08838834764831845f;

  bf16x8 kreg[8], vreg[8];
  auto load_tiles = [&](int it) {
    const int k0 = it * 64;
#pragma unroll
    for (int i = 0; i < 8; i++) {
      const int c = tid + i * 128;
      kreg[i] = *(const bf16x8*)(Kws + (size_t)(b * T_ + k0 + (c >> 4)) * D_ +
                                 (c & 15) * 8);
    }
#pragma unroll
    for (int i = 0; i < 8; i++) {
      const int c = tid + i * 128;
      vreg[i] = *(const bf16x8*)(Vtws + (size_t)(b * D_ + (c >> 3)) * T_ + k0 +
                                 (c & 7) * 8);
    }
  };
  auto write_lds = [&]() {
#pragma unroll
    for (int i = 0; i < 8; i++) {
      const int c = tid + i * 128;
      *(bf16x8*)&Ks[(c >> 4) * 136 + (c & 15) * 8] = kreg[i];
    }
#pragma unroll
    for (int i = 0; i < 8; i++) {
      const int c = tid + i * 128;
      *(bf16x8*)&Vts[(c >> 3) * 72 + (c & 7) * 8] = vreg[i];
    }
  };

  load_tiles(t0);
  for (int it = t0; it < t1; it++) {
    write_lds();
    __syncthreads();
    if (it + 1 < t1) load_tiles(it + 1);   // overlaps with compute below

    const int k0 = it * 64;
    f32x4 s[4];
#pragma unroll
    for (int nb = 0; nb < 4; nb++) s[nb] = 0.0f;
#pragma unroll
    for (int nb = 0; nb < 4; nb++) {
#pragma unroll
      for (int kc = 0; kc < 4; kc++) {
        bf16x8 bk = *(const bf16x8*)&Ks[(nb * 16 + lm) * 136 + kc * 32 + g * 8];
        s[nb] = __builtin_amdgcn_mfma_f32_16x16x32_bf16(qf[kc], bk, s[nb], 0, 0, 0);
      }
    }

    const bool diag = (it == tiles - 1);
#pragma unroll
    for (int r = 0; r < 4; r++) {
      const int qrow = q0 + wv * 16 + g * 4 + r;
      float sv[4];
#pragma unroll
      for (int nb = 0; nb < 4; nb++) {
        sv[nb] = s[nb][r] * sc;
        if (diag && (k0 + nb * 16 + lm > qrow)) sv[nb] = -1e30f;
      }
      float tm = fmaxf(fmaxf(sv[0], sv[1]), fmaxf(sv[2], sv[3]));
      tm = fmaxf(tm, __shfl_xor(tm, 1, 64));
      tm = fmaxf(tm, __shfl_xor(tm, 2, 64));
      tm = fmaxf(tm, __shfl_xor(tm, 4, 64));
      tm = fmaxf(tm, __shfl_xor(tm, 8, 64));
      const float mnew = fmaxf(m_r[r], tm);
      const float alpha = __expf(m_r[r] - mnew);
      float p[4], rs = 0.0f;
#pragma unroll
      for (int nb = 0; nb < 4; nb++) { p[nb] = __expf(sv[nb] - mnew); rs += p[nb]; }
      rs += __shfl_xor(rs, 1, 64);
      rs += __shfl_xor(rs, 2, 64);
      rs += __shfl_xor(rs, 4, 64);
      rs += __shfl_xor(rs, 8, 64);
      l_r[r] = l_r[r] * alpha + rs;
      m_r[r] = mnew;
#pragma unroll
      for (int nb2 = 0; nb2 < 8; nb2++) o[nb2][r] *= alpha;
#pragma unroll
      for (int nb = 0; nb < 4; nb++)
        Ps[wv * 1152 + (g * 4 + r) * 72 + nb * 16 + lm] = (bf16_t)p[nb];
    }

    bf16x8 pa0 = *(const bf16x8*)&Ps[wv * 1152 + lm * 72 + g * 8];
    bf16x8 pa1 = *(const bf16x8*)&Ps[wv * 1152 + lm * 72 + 32 + g * 8];
#pragma unroll
    for (int nb2 = 0; nb2 < 8; nb2++) {
      bf16x8 bv0 = *(const bf16x8*)&Vts[(nb2 * 16 + lm) * 72 + g * 8];
      o[nb2] = __builtin_amdgcn_mfma_f32_16x16x32_bf16(pa0, bv0, o[nb2], 0, 0, 0);
      bf16x8 bv1 = *(const bf16x8*)&Vts[(nb2 * 16 + lm) * 72 + 32 + g * 8];
      o[nb2] = __builtin_amdgcn_mfma_f32_16x16x32_bf16(pa1, bv1, o[nb2], 0, 0, 0);
    }
    __syncthreads();
  }

#pragma unroll
  for (int r = 0; r < 4; r++) {
    const int row = wv * 16 + g * 4 + r;
    if (lm == 0) {
      Mpart[slot * 32 + row] = m_r[r];
      Lpart[slot * 32 + row] = l_r[r];
    }
    float* dst = Opart + ((size_t)slot * 32 + row) * D_;
#pragma unroll
    for (int nb2 = 0; nb2 < 8; nb2++) dst[nb2 * 16 + lm] = o[nb2][r];
  }
}

// ---------------------------------------------------------------------------
// Kernel 2b: combine partials. grid (T/32, B), block 256. (unchanged)
// ---------------------------------------------------------------------------
__global__ __launch_bounds__(256) void attn_combine_kernel(
    const float* __restrict__ Opart, const float* __restrict__ Mpart,
    const float* __restrict__ Lpart, float* __restrict__ Out) {
  const int qi = blockIdx.x;
  const int b = blockIdx.y;
  const int gg = qi >> 4;
  const int nc = gg + 1;
  const int base = b * UNITS_PER_B + ((gg * (gg + 1)) / 2) * 16 + (qi & 15) * nc;
  const int t = threadIdx.x;
  const int row = t >> 3;
  const int d0 = (t & 7) * 16;

  float mv[4];
  float mmax = -1e30f;
  for (int ci = 0; ci < nc; ci++) {
    mv[ci] = Mpart[(base + ci) * 32 + row];
    mmax = fmaxf(mmax, mv[ci]);
  }
  f32x4 acc[4];
#pragma unroll
  for (int j = 0; j < 4; j++) acc[j] = 0.0f;
  float l = 0.0f;
  for (int ci = 0; ci < nc; ci++) {
    const float w = __expf(mv[ci] - mmax);
    l += w * Lpart[(base + ci) * 32 + row];
    const float* op = Opart + ((size_t)(base + ci) * 32 + row) * D_ + d0;
#pragma unroll
    for (int j = 0; j < 4; j++) {
      float4 v = *(const float4*)(op + j * 4);
      acc[j][0] += w * v.x; acc[j][1] += w * v.y;
      acc[j][2] += w * v.z; acc[j][3] += w * v.w;
    }
  }
  const float inv = 1.0f / l;
  float* dst = Out + ((size_t)(b * T_ + qi * 32 + row)) * D_ + d0;
#pragma unroll
  for (int j = 0; j < 4; j++) {
    float4 v;
    v.x = acc[j][0] * inv; v.y = acc[j][1] * inv;
    v.z = acc[j][2] * inv; v.w = acc[j][3] * inv;
    *(float4*)(dst + j * 4) = v;
  }
}

// ---------------------------------------------------------------------------
// Fallback proj (round-1): direct f32 inputs, M64 tile. grid (BT/64,3), 256.
// ---------------------------------------------------------------------------
__global__ __launch_bounds__(256) void proj_rope_kernel(
    const float* __restrict__ X, const float* __restrict__ Wq,
    const float* __restrict__ Wk, const float* __restrict__ Wv,
    bf16_t* __restrict__ Qws, bf16_t* __restrict__ Kws,
    bf16_t* __restrict__ Vtws) {
  const int z = blockIdx.y;
  const float* __restrict__ W = (z == 0) ? Wq : (z == 1) ? Wk : Wv;
  const int bt0 = blockIdx.x * 64;
  const int tid = threadIdx.x;
  const int lane = tid & 63;
  const int wv = tid >> 6;
  const int g = lane >> 4;
  const int lm = lane & 15;

  __shared__ bf16_t Xs[64 * 40];
  __shared__ bf16_t Ws[128 * 40];

  f32x4 acc[8];
#pragma unroll
  for (int i = 0; i < 8; i++) acc[i] = 0.0f;

  for (int kk = 0; kk < E_ / 32; kk++) {
    {
      const int row = tid >> 2, c0 = (tid & 3) * 8;
      const float* src = X + (size_t)(bt0 + row) * E_ + kk * 32 + c0;
      float4 u = *(const float4*)src;
      float4 v = *(const float4*)(src + 4);
      *(bf16x8*)&Xs[row * 40 + c0] = cvt8(u, v);
    }
#pragma unroll
    for (int h = 0; h < 2; h++) {
      const int cc = tid * 2 + h;
      const int row = cc >> 2, c0 = (cc & 3) * 8;
      const float* src = W + (size_t)row * E_ + kk * 32 + c0;
      float4 u = *(const float4*)src;
      float4 v = *(const float4*)(src + 4);
      *(bf16x8*)&Ws[row * 40 + c0] = cvt8(u, v);
    }
    __syncthreads();
    bf16x8 a = *(const bf16x8*)&Xs[(wv * 16 + lm) * 40 + g * 8];
#pragma unroll
    for (int nb = 0; nb < 8; nb++) {
      bf16x8 bb = *(const bf16x8*)&Ws[(nb * 16 + lm) * 40 + g * 8];
      acc[nb] = __builtin_amdgcn_mfma_f32_16x16x32_bf16(a, bb, acc[nb], 0, 0, 0);
    }
    __syncthreads();
  }
  const float NLOG_ = -0.14391156514261485f;
#pragma unroll
  for (int nb = 0; nb < 8; nb++) {
    const int col = nb * 16 + lm;
    const float freq = expf(NLOG_ * (float)(col >> 1));
#pragma unroll
    for (int r = 0; r < 4; r++) {
      const int bt = bt0 + wv * 16 + g * 4 + r;
      float val = acc[nb][r];
      float prt = __shfl_xor(val, 1, 64);
      if (z < 2) {
        const int t = bt & (T_ - 1);
        const float ang = (float)t * freq;
        float sn, cs;
        sincosf(ang, &sn, &cs);
        const float outv = (col & 1) ? (prt * sn + val * cs) : (val * cs - prt * sn);
        bf16_t* dst = (z == 0) ? Qws : Kws;
        dst[(size_t)bt * D_ + col] = (bf16_t)outv;
      } else {
        const int b = bt >> 11, t = bt & (T_ - 1);
        Vtws[((size_t)(b * D_ + col)) * T_ + t] = (bf16_t)val;
      }
    }
  }
}

// ---------------------------------------------------------------------------
// Fallback: single-pass flash attention (round-1 kernel)
// ---------------------------------------------------------------------------
__global__ __launch_bounds__(128) void attn_kernel(
    const bf16_t* __restrict__ Qws, const bf16_t* __restrict__ Kws,
    const bf16_t* __restrict__ Vtws, float* __restrict__ Out) {
  const int b = blockIdx.y;
  const int qi = blockIdx.x;
  const int q0 = qi * 32;
  const int tid = threadIdx.x;
  const int lane = tid & 63;
  const int wv = tid >> 6;
  const int g = lane >> 4;
  const int lm = lane & 15;

  __shared__ bf16_t Ks[32 * 136];
  __shared__ bf16_t Vts[128 * 40];
  __shared__ bf16_t Ps[2 * 16 * 40];

  bf16x8 qf[4];
  {
    const bf16_t* qb = Qws + (size_t)(b * T_ + q0 + wv * 16 + lm) * D_;
#pragma unroll
    for (int kk = 0; kk < 4; kk++) qf[kk] = *(const bf16x8*)(qb + kk * 32 + g * 8);
  }
  f32x4 o[8];
#pragma unroll
  for (int i = 0; i < 8; i++) o[i] = 0.0f;
  float m_r[4], l_r[4];
#pragma unroll
  for (int r = 0; r < 4; r++) { m_r[r] = -1e30f; l_r[r] = 0.0f; }
  const float sc = 0.08838834764831845f;

  for (int kt = 0; kt <= qi; kt++) {
    const int kv0 = kt * 32;
#pragma unroll
    for (int i = 0; i < 4; i++) {
      const int c = tid + i * 128;
      const int row = c >> 4, part = c & 15;
      bf16x8 v = *(const bf16x8*)(Kws + (size_t)(b * T_ + kv0 + row) * D_ + part * 8);
      *(bf16x8*)&Ks[row * 136 + part * 8] = v;
    }
#pragma unroll
    for (int i = 0; i < 4; i++) {
      const int c = tid + i * 128;
      const int d = c >> 2, part = c & 3;
      bf16x8 v = *(const bf16x8*)(Vtws + (size_t)(b * D_ + d) * T_ + kv0 + part * 8);
      *(bf16x8*)&Vts[d * 40 + part * 8] = v;
    }
    __syncthreads();
    f32x4 s[2];
    s[0] = 0.0f; s[1] = 0.0f;
#pragma unroll
    for (int nb = 0; nb < 2; nb++) {
#pragma unroll
      for (int kc = 0; kc < 4; kc++) {
        bf16x8 bk = *(const bf16x8*)&Ks[(nb * 16 + lm) * 136 + kc * 32 + g * 8];
        s[nb] = __builtin_amdgcn_mfma_f32_16x16x32_bf16(qf[kc], bk, s[nb], 0, 0, 0);
      }
    }
    const bool diag = (kt == qi);
#pragma unroll
    for (int r = 0; r < 4; r++) {
      float sv0 = s[0][r] * sc;
      float sv1 = s[1][r] * sc;
      if (diag) {
        const int rowr = wv * 16 + g * 4 + r;
        if (lm > rowr) sv0 = -1e30f;
        if (lm + 16 > rowr) sv1 = -1e30f;
      }
      float tm = fmaxf(sv0, sv1);
      tm = fmaxf(tm, __shfl_xor(tm, 1, 64));
      tm = fmaxf(tm, __shfl_xor(tm, 2, 64));
      tm = fmaxf(tm, __shfl_xor(tm, 4, 64));
      tm = fmaxf(tm, __shfl_xor(tm, 8, 64));
      const float mnew = fmaxf(m_r[r], tm);
      const float alpha = __expf(m_r[r] - mnew);
      const float p0 = __expf(sv0 - mnew);
      const float p1 = __expf(sv1 - mnew);
      float rs = p0 + p1;
      rs += __shfl_xor(rs, 1, 64);
      rs += __shfl_xor(rs, 2, 64);
      rs += __shfl_xor(rs, 4, 64);
      rs += __shfl_xor(rs, 8, 64);
      l_r[r] = l_r[r] * alpha + rs;
      m_r[r] = mnew;
#pragma unroll
      for (int nb2 = 0; nb2 < 8; nb2++) o[nb2][r] *= alpha;
      Ps[wv * 640 + (g * 4 + r) * 40 + lm] = (bf16_t)p0;
      Ps[wv * 640 + (g * 4 + r) * 40 + 16 + lm] = (bf16_t)p1;
    }
    bf16x8 pa = *(const bf16x8*)&Ps[wv * 640 + lm * 40 + g * 8];
#pragma unroll
    for (int nb2 = 0; nb2 < 8; nb2++) {
      bf16x8 bv = *(const bf16x8*)&Vts[(nb2 * 16 + lm) * 40 + g * 8];
      o[nb2] = __builtin_amdgcn_mfma_f32_16x16x32_bf16(pa, bv, o[nb2], 0, 0, 0);
    }
    __syncthreads();
  }
#pragma unroll
  for (int r = 0; r < 4; r++) {
    const float inv = 1.0f / l_r[r];
    float* dst = Out + (size_t)(b * T_ + q0 + wv * 16 + g * 4 + r) * D_;
#pragma unroll
    for (int nb2 = 0; nb2 < 8; nb2++) dst[nb2 * 16 + lm] = o[nb2][r] * inv;
  }
}

extern "C" void kernel_launch(void* const* d_in, const int* in_sizes, int n_in,
                              void* d_out, int out_size, void* d_ws,
                              size_t ws_size, hipStream_t stream) {
  const float* X = (const float*)d_in[0];
  const float* Wq = (const float*)d_in[1];
  const float* Wk = (const float*)d_in[2];
  const float* Wv = (const float*)d_in[3];
  float* Out = (float*)d_out;

  const size_t wb_bytes = (size_t)3 * D_ * E_ * sizeof(bf16_t);    // 0.75 MB
  const size_t qkv_bytes = (size_t)3 * BT_ * D_ * sizeof(bf16_t);  // 6 MB
  const size_t opart_bytes = (size_t)UNITS * 32 * D_ * sizeof(float);  // 10 MB
  const size_t ml_bytes = (size_t)UNITS * 32 * sizeof(float);
  const size_t tab_bytes = (size_t)T_ * 64 * sizeof(float2);       // 1 MB

  const size_t needA =
      wb_bytes + qkv_bytes + opart_bytes + 2 * ml_bytes + tab_bytes;
  const size_t needB = qkv_bytes + opart_bytes + 2 * ml_bytes;

  if (ws_size >= needA) {
    bf16_t* Wb = (bf16_t*)d_ws;
    bf16_t* Qws = Wb + (size_t)3 * D_ * E_;
    bf16_t* Kws = Qws + (size_t)BT_ * D_;
    bf16_t* Vtws = Kws + (size_t)BT_ * D_;
    float* Opart = (float*)((char*)d_ws + wb_bytes + qkv_bytes);
    float* Mpart = (float*)((char*)Opart + opart_bytes);
    float* Lpart = (float*)((char*)Mpart + ml_bytes);
    float2* Tab = (float2*)((char*)Lpart + ml_bytes);

    hipLaunchKernelGGL(wtab_kernel, dim3(256), dim3(256), 0, stream,
                       Wq, Wk, Wv, Wb, Tab);
    hipLaunchKernelGGL(proj64_kernel, dim3(768), dim3(256), 0, stream,
                       X, Wb, Tab, Qws, Kws, Vtws);
    hipLaunchKernelGGL(attn_part_kernel, dim3(UNITS), dim3(128), 0, stream,
                       Qws, Kws, Vtws, Opart, Mpart, Lpart);
    hipLaunchKernelGGL(attn_combine_kernel, dim3(T_ / 32, B_), dim3(256), 0,
                       stream, Opart, Mpart, Lpart, Out);
  } else if (ws_size >= needB) {
    bf16_t* Qws = (bf16_t*)d_ws;
    bf16_t* Kws = Qws + (size_t)BT_ * D_;
    bf16_t* Vtws = Kws + (size_t)BT_ * D_;
    float* Opart = (float*)((char*)d_ws + qkv_bytes);
    float* Mpart = (float*)((char*)Opart + opart_bytes);
    float* Lpart = (float*)((char*)Mpart + ml_bytes);
    hipLaunchKernelGGL(proj_rope_kernel, dim3(BT_ / 64, 3), dim3(256), 0,
                       stream, X, Wq, Wk, Wv, Qws, Kws, Vtws);
    hipLaunchKernelGGL(attn_part_kernel, dim3(UNITS), dim3(128), 0, stream,
                       Qws, Kws, Vtws, Opart, Mpart, Lpart);
    hipLaunchKernelGGL(attn_combine_kernel, dim3(T_ / 32, B_), dim3(256), 0,
                       stream, Opart, Mpart, Lpart, Out);
  } else {
    bf16_t* Qws = (bf16_t*)d_ws;
    bf16_t* Kws = Qws + (size_t)BT_ * D_;
    bf16_t* Vtws = Kws + (size_t)BT_ * D_;
    hipLaunchKernelGGL(proj_rope_kernel, dim3(BT_ / 64, 3), dim3(256), 0,
                       stream, X, Wq, Wk, Wv, Qws, Kws, Vtws);
    hipLaunchKernelGGL(attn_kernel, dim3(T_ / 32, B_), dim3(128), 0, stream,
                       Qws, Kws, Vtws, Out);
  }
}